// Round 14
// baseline (203.364 us; speedup 1.0000x reference)
//
#include <hip/hip_runtime.h>
#include <math.h>

// Problem constants
#define NB 48      // batch*nodes
#define HD 256     // hidden
#define TS 512     // timesteps
// 2T-1 = 1023 relative positions; embT padded to 1056 cols

typedef _Float16 f16x8 __attribute__((ext_vector_type(8)));
typedef float    f32x4 __attribute__((ext_vector_type(4)));

__device__ inline unsigned short f2h(float f) {       // f32 -> fp16 bits (RNE)
  union { _Float16 h; unsigned short u; } v; v.h = (_Float16)f; return v.u;
}
__device__ inline float h2f(unsigned short u) {
  union { unsigned short u; _Float16 h; } v; v.u = u; return (float)v.h;
}

#define ETS 1056   // embT row stride (cols 1023..1055 never read; finite fill)

// async global->LDS, 16B per lane (GEMM staging)
__device__ __forceinline__ void gll16(const void* g, void* l) {
  __builtin_amdgcn_global_load_lds(
      (const __attribute__((address_space(1))) unsigned int*)g,
      (__attribute__((address_space(3))) unsigned int*)l, 16, 0, 0);
}

// ---------------------------------------------------------------------------
// k_prep: 1D grid 1792 blocks x 256 thr
//   [0,128)     sincos table SC[1024][256] fp16 (row 1023 = 0)
//   [128,1664)  h [48,256,512] f32 -> hmH [24576][256] fp16 (+ zero vx)
//   [1664,1792) 8 weights f32 [256][256] -> fp16 transposed [N][K]
// ---------------------------------------------------------------------------
__global__ __launch_bounds__(256) void k_prep(
    const float* __restrict__ h, unsigned short* __restrict__ hmH,
    float* __restrict__ vxZ,
    const float* __restrict__ w0, const float* __restrict__ w1,
    const float* __restrict__ w2, const float* __restrict__ w3,
    const float* __restrict__ w4, const float* __restrict__ w5,
    const float* __restrict__ w6, const float* __restrict__ w7,
    unsigned short* __restrict__ WtH, unsigned short* __restrict__ SC)
{
  const int gid = blockIdx.x;
  const int tid = threadIdx.x;

  if (gid < 128) {                       // ---- sincos table ----
    const int cf = tid & 127, half = tid >> 7;
    const float f = expf((float)cf * (-9.210340371976184f / 127.0f));
#pragma unroll
    for (int rr = 0; rr < 8; ++rr) {
      int r = gid * 8 + rr;
      float ang = (float)(r - (TS - 1)) * f;
      float val = (r == 1023) ? 0.0f : (half ? cosf(ang) : sinf(ang));
      SC[r * 256 + tid] = f2h(val);
    }
    return;
  }
  if (gid < 1664) {                      // ---- h transpose -> hmH ----
    const int idx = gid - 128;
    const int bx = idx & 3, by = (idx >> 2) & 7, bz = idx >> 5;
    __shared__ float t[32 * 132];
    const int t0 = bx * 128, c0 = by * 32, b = bz;
    if (by == 0 && bz == 0) {            // zero vx (4 blocks x 256 x 24)
      float4* vz = (float4*)(vxZ + ((size_t)bx * 256 + tid) * 24);
#pragma unroll
      for (int i = 0; i < 6; ++i) vz[i] = make_float4(0.f, 0.f, 0.f, 0.f);
    }
#pragma unroll
    for (int i = 0; i < 4; ++i) {
      int cl = i * 8 + (tid >> 5);
      int t4 = (tid & 31) * 4;
      float4 v = *(const float4*)&h[((size_t)b * 256 + c0 + cl) * 512 + t0 + t4];
      t[cl * 132 + t4 + 0] = v.x; t[cl * 132 + t4 + 1] = v.y;
      t[cl * 132 + t4 + 2] = v.z; t[cl * 132 + t4 + 3] = v.w;
    }
    __syncthreads();
#pragma unroll
    for (int i = 0; i < 16; ++i) {
      int tl = i * 8 + (tid >> 5);
      int cl = tid & 31;
      hmH[((size_t)b * 512 + t0 + tl) * 256 + c0 + cl] = f2h(t[cl * 132 + tl]);
    }
    return;
  }
  {                                      // ---- weight transpose x8 ----
    const int idx = gid - 1664;
    const int kx = idx & 3, ny = (idx >> 2) & 3, mat = idx >> 4;
    const float* W = (mat == 0) ? w0 : (mat == 1) ? w1 : (mat == 2) ? w2 :
                     (mat == 3) ? w3 : (mat == 4) ? w4 : (mat == 5) ? w5 :
                     (mat == 6) ? w6 : w7;
    unsigned short* dst = WtH + (size_t)mat * 65536;
    __shared__ float t[64 * 68];
    const int k0 = kx * 64, n0 = ny * 64;
#pragma unroll
    for (int i = 0; i < 4; ++i) {
      int kr = i * 16 + (tid >> 4);
      int nc = (tid & 15) * 4;
      float4 v = *(const float4*)&W[(size_t)(k0 + kr) * 256 + n0 + nc];
      t[kr * 68 + nc + 0] = v.x; t[kr * 68 + nc + 1] = v.y;
      t[kr * 68 + nc + 2] = v.z; t[kr * 68 + nc + 3] = v.w;
    }
    __syncthreads();
#pragma unroll
    for (int i = 0; i < 4; ++i) {
      int nr = i * 16 + (tid >> 4);
      int kc = (tid & 15) * 4;
#pragma unroll
      for (int j = 0; j < 4; ++j)
        dst[(size_t)(n0 + nr) * 256 + k0 + kc + j] = f2h(t[(kc + j) * 68 + nr]);
    }
  }
}

// ---------------------------------------------------------------------------
// k_mlp2: fused multi-layer MLP per 64-row tile, 256 thr / 4 waves.
//   layer1 = A @ W1^T + b1 (SiLU unless W2==null)
//   W2==null (emb job): write layer1 -> outB row-major + outE transposed, done
//   else: hid in LDS Hst[64][264] fp16 -> layer2 = hid @ W2^T + b2
//         -> outB (q/k) and/or outT (Vt transposed)
//   W3 set (v job): v -> Hst, layer3 = SiLU(v @ W3^T + b3), then fused
//         vx[m] += layer3[m,:] . vxW  (shfl-reduce + atomicAdd; vx pre-zeroed)
// Staging via global_load_lds, source-swizzled col (rule #21).
// LDS: Wst 32KB + Ast 8KB + Hst 33.8KB = 74.75KB -> 2 blocks/CU.
// ---------------------------------------------------------------------------
struct MJob {
  const unsigned short* A; const unsigned short* W1; const float* b1;
  const unsigned short* W2; const float* b2;
  unsigned short* outB; unsigned short* outT; unsigned short* outE;
  const unsigned short* W3; const float* b3;
  const float* vxW; float* vxOut;
  int mMax;
};
struct MJobs { MJob j[4]; };

__global__ __launch_bounds__(256) void k_mlp2(MJobs jobs)
{
  __shared__ __align__(16) char Wst[32768];   // 256 n x 64 k fp16 (128B rows)
  __shared__ __align__(16) char Ast[8192];    // 64 m x 64 k
  __shared__ __align__(16) char Hst[64 * 528];// hid [64][264] fp16

  const MJob jb = jobs.j[blockIdx.y];
  const int m0 = blockIdx.x * 64;
  if (m0 >= jb.mMax) return;                  // block-uniform exit

  const int tid  = threadIdx.x;
  const int lane = tid & 63;
  const int w    = tid >> 6;       // 0..3, n-slice
  const int rq   = lane & 15;
  const int kq   = lane >> 4;
  const char* Ag  = (const char*)jb.A + (size_t)m0 * 512;
  const char* W1g = (const char*)jb.W1;

  f32x4 acc[4][4];
#pragma unroll
  for (int mi = 0; mi < 4; ++mi)
#pragma unroll
    for (int ni = 0; ni < 4; ++ni) acc[mi][ni] = (f32x4){0.f, 0.f, 0.f, 0.f};

  // ---- layer 1 ----
  for (int kt = 0; kt < 4; ++kt) {
    __syncthreads();
#pragma unroll
    for (int i = 0; i < 2; ++i) {            // A: 512 chunks
      int c = i * 256 + tid;
      int row = c >> 3, ch = c & 7;
      int colg = (ch * 16) ^ ((row & 7) << 4);
      gll16(Ag + (size_t)row * 512 + kt * 128 + colg, Ast + i * 4096 + w * 1024);
    }
#pragma unroll
    for (int i = 0; i < 8; ++i) {            // W1: 2048 chunks
      int c = i * 256 + tid;
      int row = c >> 3, ch = c & 7;
      int colg = (ch * 16) ^ ((row & 7) << 4);
      gll16(W1g + (size_t)row * 512 + kt * 128 + colg, Wst + i * 4096 + w * 1024);
    }
    __syncthreads();
#pragma unroll
    for (int ks = 0; ks < 2; ++ks) {
      const int kb = ks * 64 + kq * 16;
      f16x8 af[4], bfr[4];
#pragma unroll
      for (int mi = 0; mi < 4; ++mi) {
        int row = mi * 16 + rq;
        af[mi] = *(const f16x8*)(Ast + row * 128 + (kb ^ ((row & 7) << 4)));
      }
#pragma unroll
      for (int ni = 0; ni < 4; ++ni) {
        int row = w * 64 + ni * 16 + rq;
        bfr[ni] = *(const f16x8*)(Wst + row * 128 + (kb ^ ((row & 7) << 4)));
      }
#pragma unroll
      for (int mi = 0; mi < 4; ++mi)
#pragma unroll
        for (int ni = 0; ni < 4; ++ni)
          acc[mi][ni] = __builtin_amdgcn_mfma_f32_16x16x32_f16(
              af[mi], bfr[ni], acc[mi][ni], 0, 0, 0);
    }
  }

  // ---- single-layer job (emb): bias, write row-major + transposed ----
  if (!jb.W2) {
#pragma unroll
    for (int ni = 0; ni < 4; ++ni) {
      const int n = w * 64 + ni * 16 + rq;
      const float bv = jb.b1[n];
#pragma unroll
      for (int mi = 0; mi < 4; ++mi)
#pragma unroll
        for (int j = 0; j < 4; ++j) {
          float vl = acc[mi][ni][j] + bv;
          int m = m0 + mi * 16 + kq * 4 + j;
          jb.outB[(size_t)m * 256 + n] = f2h(vl);
          jb.outE[(size_t)n * ETS + m] = f2h(vl);
        }
    }
    return;
  }

  // ---- SiLU -> hid LDS ----
  {
#pragma unroll
    for (int ni = 0; ni < 4; ++ni) {
      const int n = w * 64 + ni * 16 + rq;
      const float bv = jb.b1[n];
#pragma unroll
      for (int mi = 0; mi < 4; ++mi)
#pragma unroll
        for (int j = 0; j < 4; ++j) {
          float vl = acc[mi][ni][j] + bv;
          vl = vl / (1.0f + __expf(-vl));
          int m = mi * 16 + kq * 4 + j;
          *(unsigned short*)(Hst + m * 528 + n * 2) = f2h(vl);
        }
    }
  }
#pragma unroll
  for (int mi = 0; mi < 4; ++mi)
#pragma unroll
    for (int ni = 0; ni < 4; ++ni) acc[mi][ni] = (f32x4){0.f, 0.f, 0.f, 0.f};

  // ---- layer 2 (A from hid LDS) ----
  const char* W2g = (const char*)jb.W2;
  for (int kt = 0; kt < 4; ++kt) {
    __syncthreads();   // kt=0: all layer-1 reads + hid writes complete
#pragma unroll
    for (int i = 0; i < 8; ++i) {
      int c = i * 256 + tid;
      int row = c >> 3, ch = c & 7;
      int colg = (ch * 16) ^ ((row & 7) << 4);
      gll16(W2g + (size_t)row * 512 + kt * 128 + colg, Wst + i * 4096 + w * 1024);
    }
    __syncthreads();
#pragma unroll
    for (int ks = 0; ks < 2; ++ks) {
      const int kb = ks * 64 + kq * 16;
      f16x8 af[4], bfr[4];
#pragma unroll
      for (int mi = 0; mi < 4; ++mi) {
        int row = mi * 16 + rq;
        af[mi] = *(const f16x8*)(Hst + row * 528 + kt * 128 + kb);
      }
#pragma unroll
      for (int ni = 0; ni < 4; ++ni) {
        int row = w * 64 + ni * 16 + rq;
        bfr[ni] = *(const f16x8*)(Wst + row * 128 + (kb ^ ((row & 7) << 4)));
      }
#pragma unroll
      for (int mi = 0; mi < 4; ++mi)
#pragma unroll
        for (int ni = 0; ni < 4; ++ni)
          acc[mi][ni] = __builtin_amdgcn_mfma_f32_16x16x32_f16(
              af[mi], bfr[ni], acc[mi][ni], 0, 0, 0);
    }
  }

  // ---- layer-2 epilogue: outB (q/k) and/or outT (Vt transposed) ----
  const int bb = m0 >> 9;
  const int tbase = m0 & 511;
#pragma unroll
  for (int ni = 0; ni < 4; ++ni) {
    const int n = w * 64 + ni * 16 + rq;
    const float bv = jb.b2[n];
#pragma unroll
    for (int mi = 0; mi < 4; ++mi) {
      float vl4[4];
#pragma unroll
      for (int j = 0; j < 4; ++j) vl4[j] = acc[mi][ni][j] + bv;
      if (jb.outB) {
#pragma unroll
        for (int j = 0; j < 4; ++j) {
          int m = m0 + mi * 16 + kq * 4 + j;
          jb.outB[(size_t)m * 256 + n] = f2h(vl4[j]);
        }
      }
      if (jb.outT) {
        ushort4 o;
        o.x = f2h(vl4[0]); o.y = f2h(vl4[1]);
        o.z = f2h(vl4[2]); o.w = f2h(vl4[3]);
        *(ushort4*)&jb.outT[((size_t)(bb * 256 + n) << 9) +
                            tbase + mi * 16 + kq * 4] = o;
      }
    }
  }

  if (!jb.W3) return;

  // ---- layer 3 (x-MLP on v): v -> Hst, hid2 = SiLU(v @ W3^T + b3) ----
  __syncthreads();                      // all layer-2 Hst reads complete
  {
#pragma unroll
    for (int ni = 0; ni < 4; ++ni) {
      const int n = w * 64 + ni * 16 + rq;
      const float bv = jb.b2[n];
#pragma unroll
      for (int mi = 0; mi < 4; ++mi)
#pragma unroll
        for (int j = 0; j < 4; ++j) {
          int m = mi * 16 + kq * 4 + j;
          *(unsigned short*)(Hst + m * 528 + n * 2) = f2h(acc[mi][ni][j] + bv);
        }
    }
  }
#pragma unroll
  for (int mi = 0; mi < 4; ++mi)
#pragma unroll
    for (int ni = 0; ni < 4; ++ni) acc[mi][ni] = (f32x4){0.f, 0.f, 0.f, 0.f};

  const char* W3g = (const char*)jb.W3;
  for (int kt = 0; kt < 4; ++kt) {
    __syncthreads();   // kt=0: all v -> Hst writes complete
#pragma unroll
    for (int i = 0; i < 8; ++i) {
      int c = i * 256 + tid;
      int row = c >> 3, ch = c & 7;
      int colg = (ch * 16) ^ ((row & 7) << 4);
      gll16(W3g + (size_t)row * 512 + kt * 128 + colg, Wst + i * 4096 + w * 1024);
    }
    __syncthreads();
#pragma unroll
    for (int ks = 0; ks < 2; ++ks) {
      const int kb = ks * 64 + kq * 16;
      f16x8 af[4], bfr[4];
#pragma unroll
      for (int mi = 0; mi < 4; ++mi) {
        int row = mi * 16 + rq;
        af[mi] = *(const f16x8*)(Hst + row * 528 + kt * 128 + kb);
      }
#pragma unroll
      for (int ni = 0; ni < 4; ++ni) {
        int row = w * 64 + ni * 16 + rq;
        bfr[ni] = *(const f16x8*)(Wst + row * 128 + (kb ^ ((row & 7) << 4)));
      }
#pragma unroll
      for (int mi = 0; mi < 4; ++mi)
#pragma unroll
        for (int ni = 0; ni < 4; ++ni)
          acc[mi][ni] = __builtin_amdgcn_mfma_f32_16x16x32_f16(
              af[mi], bfr[ni], acc[mi][ni], 0, 0, 0);
    }
  }

  // ---- vx epilogue: SiLU + dot with vxW, shfl-reduce, atomicAdd ----
  {
    float vxp_[4][4];
#pragma unroll
    for (int mi = 0; mi < 4; ++mi)
#pragma unroll
      for (int j = 0; j < 4; ++j) vxp_[mi][j] = 0.f;
#pragma unroll
    for (int ni = 0; ni < 4; ++ni) {
      const int n = w * 64 + ni * 16 + rq;
      const float bv = jb.b3[n];
      const float wq = jb.vxW[n];
#pragma unroll
      for (int mi = 0; mi < 4; ++mi)
#pragma unroll
        for (int j = 0; j < 4; ++j) {
          float vl = acc[mi][ni][j] + bv;
          vl = vl / (1.0f + __expf(-vl));
          vxp_[mi][j] = fmaf(vl, wq, vxp_[mi][j]);
        }
    }
#pragma unroll
    for (int mi = 0; mi < 4; ++mi)
#pragma unroll
      for (int j = 0; j < 4; ++j) {
        float s = vxp_[mi][j];
        s += __shfl_xor(s, 1); s += __shfl_xor(s, 2);
        s += __shfl_xor(s, 4); s += __shfl_xor(s, 8);
        if (rq == 0)
          atomicAdd(&jb.vxOut[m0 + mi * 16 + kq * 4 + j], s);
      }
  }
}

// ---------------------------------------------------------------------------
// MFMA fused attention (unchanged from round 13, the passing kernel).
// ---------------------------------------------------------------------------
__global__ __launch_bounds__(256, 2) void k_attn6(
    const float* __restrict__ xin, const float* __restrict__ hin,
    const unsigned short* __restrict__ qH, const unsigned short* __restrict__ kH,
    const unsigned short* __restrict__ vtH, const float* __restrict__ vxm,
    const float* __restrict__ xb2p,
    const unsigned short* __restrict__ embB, const unsigned short* __restrict__ embT,
    float* __restrict__ xout, float* __restrict__ hout)
{
  __shared__ __align__(16) char smem[70656];
  float* S  = (float*)smem;                              // [32][524]
  unsigned short* Pb = (unsigned short*)smem;            // [32][520], after S dies
  unsigned short* Pe = (unsigned short*)(smem + 33280);  // [32][584]

  const int tid  = threadIdx.x;
  const int lane = tid & 63;
  const int w    = tid >> 6;
  const int rq   = lane & 15;
  const int kq   = lane >> 4;
  const int id = blockIdx.x;
  const int t0 = ((id >> 3) & 15) * 32;
  const int b  = (id & 7) + 8 * (id >> 7);
  const int sw = w * 128;

  f16x8 q0[8], q1[8];
  {
    const size_t qo = ((size_t)(b * TS + t0 + rq) << 8) + kq * 8;
#pragma unroll
    for (int ks = 0; ks < 8; ++ks) {
      q0[ks] = *(const f16x8*)(qH + qo + ks * 32);
      q1[ks] = *(const f16x8*)(qH + qo + 4096 + ks * 32);
    }
  }

  f32x4 a0[8], a1[8];
#pragma unroll
  for (int ni = 0; ni < 8; ++ni) {
    a0[ni] = (f32x4){0.f, 0.f, 0.f, 0.f};
    a1[ni] = (f32x4){0.f, 0.f, 0.f, 0.f};
  }
  {
    const unsigned short* kp = kH + ((size_t)(b * TS + sw + rq) << 8) + kq * 8;
    f16x8 kA[8], kB[8];
#pragma unroll
    for (int ni = 0; ni < 8; ++ni) kA[ni] = *(const f16x8*)(kp + ni * 4096);
#pragma unroll
    for (int ni = 0; ni < 8; ++ni) kB[ni] = *(const f16x8*)(kp + ni * 4096 + 32);
#pragma unroll
    for (int ks = 0; ks < 8; ks += 2) {
#pragma unroll
      for (int ni = 0; ni < 8; ++ni) {
        a0[ni] = __builtin_amdgcn_mfma_f32_16x16x32_f16(q0[ks], kA[ni], a0[ni], 0, 0, 0);
        a1[ni] = __builtin_amdgcn_mfma_f32_16x16x32_f16(q1[ks], kA[ni], a1[ni], 0, 0, 0);
        if (ks + 2 < 8) kA[ni] = *(const f16x8*)(kp + ni * 4096 + (ks + 2) * 32);
      }
#pragma unroll
      for (int ni = 0; ni < 8; ++ni) {
        a0[ni] = __builtin_amdgcn_mfma_f32_16x16x32_f16(q0[ks + 1], kB[ni], a0[ni], 0, 0, 0);
        a1[ni] = __builtin_amdgcn_mfma_f32_16x16x32_f16(q1[ks + 1], kB[ni], a1[ni], 0, 0, 0);
        if (ks + 3 < 8) kB[ni] = *(const f16x8*)(kp + ni * 4096 + (ks + 3) * 32);
      }
    }
  }

  const int rbR = t0 - sw + 384;
  const unsigned short* ep = embB + ((size_t)(rbR + rq) << 8) + kq * 8;
  f16x8 eA[10], eB[10];
#pragma unroll
  for (int f = 0; f < 10; ++f) eA[f] = *(const f16x8*)(ep + f * 4096);
#pragma unroll
  for (int ni = 0; ni < 8; ++ni)
#pragma unroll
    for (int j = 0; j < 4; ++j) {
      S[(kq * 4 + j) * 524 + sw + ni * 16 + rq]        = a0[ni][j];
      S[(16 + kq * 4 + j) * 524 + sw + ni * 16 + rq]   = a1[ni][j];
    }
#pragma unroll
  for (int f = 0; f < 10; ++f) eB[f] = *(const f16x8*)(ep + f * 4096 + 32);

  f32x4 r0[9], r1[9];
#pragma unroll
  for (int ni = 0; ni < 9; ++ni) {
    r0[ni] = (f32x4){0.f, 0.f, 0.f, 0.f};
    r1[ni] = (f32x4){0.f, 0.f, 0.f, 0.f};
  }
#pragma unroll
  for (int ks = 0; ks < 8; ks += 2) {
#pragma unroll
    for (int f = 0; f < 10; ++f) {
      if (f < 9) r0[f] = __builtin_amdgcn_mfma_f32_16x16x32_f16(q0[ks], eA[f], r0[f], 0, 0, 0);
      if (f > 0) r1[f - 1] = __builtin_amdgcn_mfma_f32_16x16x32_f16(q1[ks], eA[f], r1[f - 1], 0, 0, 0);
      if (ks + 2 < 8) eA[f] = *(const f16x8*)(ep + f * 4096 + (ks + 2) * 32);
    }
#pragma unroll
    for (int f = 0; f < 10; ++f) {
      if (f < 9) r0[f] = __builtin_amdgcn_mfma_f32_16x16x32_f16(q0[ks + 1], eB[f], r0[f], 0, 0, 0);
      if (f > 0) r1[f - 1] = __builtin_amdgcn_mfma_f32_16x16x32_f16(q1[ks + 1], eB[f], r1[f - 1], 0, 0, 0);
      if (ks + 3 < 8) eB[f] = *(const f16x8*)(ep + f * 4096 + (ks + 3) * 32);
    }
  }

  asm volatile("s_waitcnt lgkmcnt(0)" ::: "memory");
  __builtin_amdgcn_sched_barrier(0);
#pragma unroll
  for (int ni = 0; ni < 9; ++ni)
#pragma unroll
    for (int j = 0; j < 4; ++j) {
      int tp  = kq * 4 + j;
      int slw = tp + 127 - (ni * 16 + rq);
      if (slw >= 0 && slw < 128) {
        S[tp * 524 + sw + slw]        += r0[ni][j];
        S[(16 + tp) * 524 + sw + slw] += r1[ni][j];
      }
    }
  __syncthreads();

  const int row16 = tid >> 4, tx = tid & 15;
  float p0[32], p1[32];
  float invl0, invl1;
#pragma unroll
  for (int pass = 0; pass < 2; ++pass) {
    float* pp = pass ? p1 : p0;
    const float* Srow = S + (pass * 16 + row16) * 524 + tx * 4;
    float mx = -3.0e38f, l = 0.f;
#pragma unroll
    for (int i = 0; i < 8; ++i) {
      float4 v = *(const float4*)(Srow + i * 64);
      pp[4*i+0] = v.x; pp[4*i+1] = v.y; pp[4*i+2] = v.z; pp[4*i+3] = v.w;
    }
#pragma unroll
    for (int i = 0; i < 32; ++i) mx = fmaxf(mx, pp[i]);
    mx = fmaxf(mx, __shfl_xor(mx, 1)); mx = fmaxf(mx, __shfl_xor(mx, 2));
    mx = fmaxf(mx, __shfl_xor(mx, 4)); mx = fmaxf(mx, __shfl_xor(mx, 8));
#pragma unroll
    for (int i = 0; i < 32; ++i) { pp[i] = __expf(pp[i] - mx); l += pp[i]; }
    l += __shfl_xor(l, 1); l += __shfl_xor(l, 2);
    l += __shfl_xor(l, 4); l += __shfl_xor(l, 8);
    if (pass) invl1 = 1.0f / l; else invl0 = 1.0f / l;
  }

  {
    const float xb2c = xb2p[0];
    const float* vxp = vxm + b * TS;
    const float* xp  = xin + (size_t)b * 3 * TS;
    float w0s = 0.f, xa00 = 0.f, xa01 = 0.f, xa02 = 0.f;
    float w1s = 0.f, xa10 = 0.f, xa11 = 0.f, xa12 = 0.f;
#pragma unroll
    for (int i = 0; i < 8; ++i) {
      int s = i * 64 + tx * 4;
      float4 vv = *(const float4*)(vxp + s);
      float4 x0 = *(const float4*)(xp + s);
      float4 x1 = *(const float4*)(xp + TS + s);
      float4 x2 = *(const float4*)(xp + 2 * TS + s);
      float vb0 = vv.x + xb2c, vb1 = vv.y + xb2c, vb2 = vv.z + xb2c, vb3 = vv.w + xb2c;
      float wv;
      wv = p0[4*i+0] * vb0; w0s += wv; xa00 = fmaf(wv, x0.x, xa00); xa01 = fmaf(wv, x1.x, xa01); xa02 = fmaf(wv, x2.x, xa02);
      wv = p0[4*i+1] * vb1; w0s += wv; xa00 = fmaf(wv, x0.y, xa00); xa01 = fmaf(wv, x1.y, xa01); xa02 = fmaf(wv, x2.y, xa02);
      wv = p0[4*i+2] * vb2; w0s += wv; xa00 = fmaf(wv, x0.z, xa00); xa01 = fmaf(wv, x1.z, xa01); xa02 = fmaf(wv, x2.z, xa02);
      wv = p0[4*i+3] * vb3; w0s += wv; xa00 = fmaf(wv, x0.w, xa00); xa01 = fmaf(wv, x1.w, xa01); xa02 = fmaf(wv, x2.w, xa02);
      wv = p1[4*i+0] * vb0; w1s += wv; xa10 = fmaf(wv, x0.x, xa10); xa11 = fmaf(wv, x1.x, xa11); xa12 = fmaf(wv, x2.x, xa12);
      wv = p1[4*i+1] * vb1; w1s += wv; xa10 = fmaf(wv, x0.y, xa10); xa11 = fmaf(wv, x1.y, xa11); xa12 = fmaf(wv, x2.y, xa12);
      wv = p1[4*i+2] * vb2; w1s += wv; xa10 = fmaf(wv, x0.z, xa10); xa11 = fmaf(wv, x1.z, xa11); xa12 = fmaf(wv, x2.z, xa12);
      wv = p1[4*i+3] * vb3; w1s += wv; xa10 = fmaf(wv, x0.w, xa10); xa11 = fmaf(wv, x1.w, xa11); xa12 = fmaf(wv, x2.w, xa12);
    }
#pragma unroll
    for (int m = 1; m < 16; m <<= 1) {
      w0s += __shfl_xor(w0s, m); xa00 += __shfl_xor(xa00, m);
      xa01 += __shfl_xor(xa01, m); xa02 += __shfl_xor(xa02, m);
      w1s += __shfl_xor(w1s, m); xa10 += __shfl_xor(xa10, m);
      xa11 += __shfl_xor(xa11, m); xa12 += __shfl_xor(xa12, m);
    }
    if (tx == 0) {
      int ta = t0 + row16, tb2 = t0 + 16 + row16;
      float wsa = w0s * invl0, wsb = w1s * invl1;
      xout[(b * 3 + 0) * TS + ta] = xp[ta]          * (1.0f + wsa) - xa00 * invl0;
      xout[(b * 3 + 1) * TS + ta] = xp[TS + ta]     * (1.0f + wsa) - xa01 * invl0;
      xout[(b * 3 + 2) * TS + ta] = xp[2 * TS + ta] * (1.0f + wsa) - xa02 * invl0;
      xout[(b * 3 + 0) * TS + tb2] = xp[tb2]          * (1.0f + wsb) - xa10 * invl1;
      xout[(b * 3 + 1) * TS + tb2] = xp[TS + tb2]     * (1.0f + wsb) - xa11 * invl1;
      xout[(b * 3 + 2) * TS + tb2] = xp[2 * TS + tb2] * (1.0f + wsb) - xa12 * invl1;
    }
  }
  __syncthreads();

  {
    unsigned int* pz = (unsigned int*)Pe;
    for (int i = tid; i < 9344; i += 256) pz[i] = 0u;
  }
  __syncthreads();

#pragma unroll
  for (int pass = 0; pass < 2; ++pass) {
    const float* pp = pass ? p1 : p0;
    const float il = pass ? invl1 : invl0;
    const int row = pass * 16 + row16;
    unsigned short* pbrow = Pb + row * 520 + tx * 4;
    unsigned short* perow = Pe + row * 584 + row + 511;
#pragma unroll
    for (int i = 0; i < 8; ++i) {
      int s = i * 64 + tx * 4;
      ushort4 pu;
      pu.x = f2h(pp[4*i+0] * il); pu.y = f2h(pp[4*i+1] * il);
      pu.z = f2h(pp[4*i+2] * il); pu.w = f2h(pp[4*i+3] * il);
      *(ushort4*)(pbrow + i * 64) = pu;
      perow[-(s + 0)] = pu.x; perow[-(s + 1)] = pu.y;
      perow[-(s + 2)] = pu.z; perow[-(s + 3)] = pu.w;
    }
  }
  __syncthreads();

  const int n0 = w * 64;
  f32x4 o0[4], o1[4];
#pragma unroll
  for (int ni = 0; ni < 4; ++ni) {
    o0[ni] = (f32x4){0.f, 0.f, 0.f, 0.f};
    o1[ni] = (f32x4){0.f, 0.f, 0.f, 0.f};
  }
  {
    const unsigned short* pb0 = Pb + rq * 520 + kq * 8;
    const unsigned short* pb1 = Pb + (16 + rq) * 520 + kq * 8;
    const unsigned short* pe0 = Pe + rq * 584 + kq * 8;
    const unsigned short* pe1 = Pe + (16 + rq) * 584 + kq * 8;
    const unsigned short* vtp = vtH + ((size_t)(b * 256 + n0 + rq) << 9) + kq * 8;
    const unsigned short* etp = embT + (size_t)(n0 + rq) * ETS + t0 + kq * 8;
    f16x8 vA[4], vB[4], gA[4], gB[4];
#pragma unroll
    for (int ni = 0; ni < 4; ++ni) {
      vA[ni] = *(const f16x8*)(vtp + ni * 8192);
      gA[ni] = *(const f16x8*)(etp + ni * 16 * ETS);
      vB[ni] = *(const f16x8*)(vtp + ni * 8192 + 32);
      gB[ni] = *(const f16x8*)(etp + ni * 16 * ETS + 32);
    }
#pragma unroll
    for (int kk = 0; kk < 16; kk += 2) {
      f16x8 pa0 = *(const f16x8*)(pb0 + kk * 32);
      f16x8 pa1 = *(const f16x8*)(pb1 + kk * 32);
#pragma unroll
      for (int ni = 0; ni < 4; ++ni) {
        o0[ni] = __builtin_amdgcn_mfma_f32_16x16x32_f16(pa0, vA[ni], o0[ni], 0, 0, 0);
        o1[ni] = __builtin_amdgcn_mfma_f32_16x16x32_f16(pa1, vA[ni], o1[ni], 0, 0, 0);
        if (kk + 2 < 16) vA[ni] = *(const f16x8*)(vtp + ni * 8192 + (kk + 2) * 32);
      }
      f16x8 pe0f = *(const f16x8*)(pe0 + kk * 32);
      f16x8 pe1f = *(const f16x8*)(pe1 + kk * 32);
#pragma unroll
      for (int ni = 0; ni < 4; ++ni) {
        o0[ni] = __builtin_amdgcn_mfma_f32_16x16x32_f16(pe0f, gA[ni], o0[ni], 0, 0, 0);
        o1[ni] = __builtin_amdgcn_mfma_f32_16x16x32_f16(pe1f, gA[ni], o1[ni], 0, 0, 0);
        if (kk + 2 < 17) gA[ni] = *(const f16x8*)(etp + ni * 16 * ETS + (kk + 2) * 32);
      }
      f16x8 pc0 = *(const f16x8*)(pb0 + (kk + 1) * 32);
      f16x8 pc1 = *(const f16x8*)(pb1 + (kk + 1) * 32);
#pragma unroll
      for (int ni = 0; ni < 4; ++ni) {
        o0[ni] = __builtin_amdgcn_mfma_f32_16x16x32_f16(pc0, vB[ni], o0[ni], 0, 0, 0);
        o1[ni] = __builtin_amdgcn_mfma_f32_16x16x32_f16(pc1, vB[ni], o1[ni], 0, 0, 0);
        if (kk + 3 < 16) vB[ni] = *(const f16x8*)(vtp + ni * 8192 + (kk + 3) * 32);
      }
      f16x8 pd0 = *(const f16x8*)(pe0 + (kk + 1) * 32);
      f16x8 pd1 = *(const f16x8*)(pe1 + (kk + 1) * 32);
#pragma unroll
      for (int ni = 0; ni < 4; ++ni) {
        o0[ni] = __builtin_amdgcn_mfma_f32_16x16x32_f16(pd0, gB[ni], o0[ni], 0, 0, 0);
        o1[ni] = __builtin_amdgcn_mfma_f32_16x16x32_f16(pd1, gB[ni], o1[ni], 0, 0, 0);
        if (kk + 3 < 17) gB[ni] = *(const f16x8*)(etp + ni * 16 * ETS + (kk + 3) * 32);
      }
    }
    f16x8 pt0 = *(const f16x8*)(pe0 + 16 * 32);
    f16x8 pt1 = *(const f16x8*)(pe1 + 16 * 32);
#pragma unroll
    for (int ni = 0; ni < 4; ++ni) {
      o0[ni] = __builtin_amdgcn_mfma_f32_16x16x32_f16(pt0, gA[ni], o0[ni], 0, 0, 0);
      o1[ni] = __builtin_amdgcn_mfma_f32_16x16x32_f16(pt1, gA[ni], o1[ni], 0, 0, 0);
    }
  }

  {
#pragma unroll
    for (int ni = 0; ni < 4; ++ni) {
      int hh = n0 + ni * 16 + rq;
      size_t base = (((size_t)(b * 256 + hh)) << 9) + t0 + kq * 4;
      float4 hv0 = *(const float4*)(hin + base);
      float4 ov0;
      ov0.x = hv0.x + o0[ni][0];
      ov0.y = hv0.y + o0[ni][1];
      ov0.z = hv0.z + o0[ni][2];
      ov0.w = hv0.w + o0[ni][3];
      *(float4*)(hout + base) = ov0;
      float4 hv1 = *(const float4*)(hin + base + 16);
      float4 ov1;
      ov1.x = hv1.x + o1[ni][0];
      ov1.y = hv1.y + o1[ni][1];
      ov1.z = hv1.z + o1[ni][2];
      ov1.w = hv1.w + o1[ni][3];
      *(float4*)(hout + base + 16) = ov1;
    }
  }
}

// ---------------------------------------------------------------------------
extern "C" void kernel_launch(void* const* d_in, const int* in_sizes, int n_in,
                              void* d_out, int out_size, void* d_ws, size_t ws_size,
                              hipStream_t stream)
{
  const float* x   = (const float*)d_in[0];
  const float* h   = (const float*)d_in[1];
  const float* qW1 = (const float*)d_in[2];
  const float* qb1 = (const float*)d_in[3];
  const float* qW2 = (const float*)d_in[4];
  const float* qb2 = (const float*)d_in[5];
  const float* kW1 = (const float*)d_in[6];
  const float* kb1 = (const float*)d_in[7];
  const float* kW2 = (const float*)d_in[8];
  const float* kb2 = (const float*)d_in[9];
  const float* vW1 = (const float*)d_in[10];
  const float* vb1 = (const float*)d_in[11];
  const float* vW2 = (const float*)d_in[12];
  const float* vb2 = (const float*)d_in[13];
  const float* xW1 = (const float*)d_in[14];
  const float* xb1 = (const float*)d_in[15];
  const float* xW2 = (const float*)d_in[16];
  const float* xb2 = (const float*)d_in[17];
  const float* teW = (const float*)d_in[18];
  const float* teb = (const float*)d_in[19];

  // ws layout (fp16 except vx) ~54 MB
  unsigned short* cur = (unsigned short*)d_ws;
  unsigned short* embB = cur; cur += 1024 * 256;
  unsigned short* embT = cur; cur += 256 * ETS;
  unsigned short* SC   = cur; cur += 1024 * 256;
  unsigned short* hmH  = cur; cur += (size_t)24576 * 256;
  unsigned short* WtH  = cur; cur += 8 * 65536;
  unsigned short* qHp  = cur; cur += (size_t)24576 * 256;
  unsigned short* kHp  = cur; cur += (size_t)24576 * 256;
  unsigned short* vtH  = cur; cur += (size_t)24576 * 256;
  float* vx = (float*)cur;                                // 24576 f32

  float* xout = (float*)d_out;                // [48,3,512]
  float* hout = xout + NB * 3 * TS;           // [48,256,512]

  // 1) all preps (sincos | h->hmH+vx-zero | 8x weight transpose)
  k_prep<<<1792, 256, 0, stream>>>(h, hmH, vx,
                                   qW1, qW2, kW1, kW2, vW1, vW2, xW1, teW,
                                   WtH, SC);

  // 2) all GEMM work in one launch:
  //    q (2-layer), k (2-layer), v (2-layer + x-MLP 3rd layer + vx), emb (1-layer)
  {
    MJobs jm{{
      {hmH, WtH + 0 * 65536, qb1, WtH + 1 * 65536, qb2,
       qHp, nullptr, nullptr, nullptr, nullptr, nullptr, nullptr, 24576},
      {hmH, WtH + 2 * 65536, kb1, WtH + 3 * 65536, kb2,
       kHp, nullptr, nullptr, nullptr, nullptr, nullptr, nullptr, 24576},
      {hmH, WtH + 4 * 65536, vb1, WtH + 5 * 65536, vb2,
       nullptr, vtH, nullptr, WtH + 6 * 65536, xb1, xW2, vx, 24576},
      {SC,  WtH + 7 * 65536, teb, nullptr, nullptr,
       embB, nullptr, embT, nullptr, nullptr, nullptr, nullptr, 1024}
    }};
    k_mlp2<<<dim3(384, 4), 256, 0, stream>>>(jm);
  }

  // 3) fused attention (unchanged)
  k_attn6<<<768, 256, 0, stream>>>(x, h, qHp, kHp, vtH, vx, xb2,
                                   embB, embT, xout, hout);
}

// Round 15
// 190.245 us; speedup vs baseline: 1.0690x; 1.0690x over previous
//
#include <hip/hip_runtime.h>
#include <math.h>

// Problem constants
#define NB 48      // batch*nodes
#define HD 256     // hidden
#define TS 512     // timesteps
// 2T-1 = 1023 relative positions; embT padded to 1056 cols

typedef _Float16 f16x8 __attribute__((ext_vector_type(8)));
typedef float    f32x4 __attribute__((ext_vector_type(4)));

__device__ inline unsigned short f2h(float f) {       // f32 -> fp16 bits (RNE)
  union { _Float16 h; unsigned short u; } v; v.h = (_Float16)f; return v.u;
}
__device__ inline float h2f(unsigned short u) {
  union { unsigned short u; _Float16 h; } v; v.u = u; return (float)v.h;
}

#define ETS 1056   // embT row stride (cols 1023..1055 never read; finite fill)

// async global->LDS, 16B per lane (GEMM staging)
__device__ __forceinline__ void gll16(const void* g, void* l) {
  __builtin_amdgcn_global_load_lds(
      (const __attribute__((address_space(1))) unsigned int*)g,
      (__attribute__((address_space(3))) unsigned int*)l, 16, 0, 0);
}

// ---------------------------------------------------------------------------
// k_prep: 1D grid 1792 blocks x 256 thr
//   [0,128)     sincos table SC[1024][256] fp16 (row 1023 = 0)
//   [128,1664)  h [48,256,512] f32 -> hmH [24576][256] fp16 (+ zero vx)
//   [1664,1792) 8 weights f32 [256][256] -> fp16 transposed [N][K]
// ---------------------------------------------------------------------------
__global__ __launch_bounds__(256) void k_prep(
    const float* __restrict__ h, unsigned short* __restrict__ hmH,
    float* __restrict__ vxZ,
    const float* __restrict__ w0, const float* __restrict__ w1,
    const float* __restrict__ w2, const float* __restrict__ w3,
    const float* __restrict__ w4, const float* __restrict__ w5,
    const float* __restrict__ w6, const float* __restrict__ w7,
    unsigned short* __restrict__ WtH, unsigned short* __restrict__ SC)
{
  const int gid = blockIdx.x;
  const int tid = threadIdx.x;

  if (gid < 128) {                       // ---- sincos table ----
    const int cf = tid & 127, half = tid >> 7;
    const float f = expf((float)cf * (-9.210340371976184f / 127.0f));
#pragma unroll
    for (int rr = 0; rr < 8; ++rr) {
      int r = gid * 8 + rr;
      float ang = (float)(r - (TS - 1)) * f;
      float val = (r == 1023) ? 0.0f : (half ? cosf(ang) : sinf(ang));
      SC[r * 256 + tid] = f2h(val);
    }
    return;
  }
  if (gid < 1664) {                      // ---- h transpose -> hmH ----
    const int idx = gid - 128;
    const int bx = idx & 3, by = (idx >> 2) & 7, bz = idx >> 5;
    __shared__ float t[32 * 132];
    const int t0 = bx * 128, c0 = by * 32, b = bz;
    if (by == 0 && bz == 0) {            // zero vx (4 blocks x 256 x 24)
      float4* vz = (float4*)(vxZ + ((size_t)bx * 256 + tid) * 24);
#pragma unroll
      for (int i = 0; i < 6; ++i) vz[i] = make_float4(0.f, 0.f, 0.f, 0.f);
    }
#pragma unroll
    for (int i = 0; i < 4; ++i) {
      int cl = i * 8 + (tid >> 5);
      int t4 = (tid & 31) * 4;
      float4 v = *(const float4*)&h[((size_t)b * 256 + c0 + cl) * 512 + t0 + t4];
      t[cl * 132 + t4 + 0] = v.x; t[cl * 132 + t4 + 1] = v.y;
      t[cl * 132 + t4 + 2] = v.z; t[cl * 132 + t4 + 3] = v.w;
    }
    __syncthreads();
#pragma unroll
    for (int i = 0; i < 16; ++i) {
      int tl = i * 8 + (tid >> 5);
      int cl = tid & 31;
      hmH[((size_t)b * 512 + t0 + tl) * 256 + c0 + cl] = f2h(t[cl * 132 + tl]);
    }
    return;
  }
  {                                      // ---- weight transpose x8 ----
    const int idx = gid - 1664;
    const int kx = idx & 3, ny = (idx >> 2) & 3, mat = idx >> 4;
    const float* W = (mat == 0) ? w0 : (mat == 1) ? w1 : (mat == 2) ? w2 :
                     (mat == 3) ? w3 : (mat == 4) ? w4 : (mat == 5) ? w5 :
                     (mat == 6) ? w6 : w7;
    unsigned short* dst = WtH + (size_t)mat * 65536;
    __shared__ float t[64 * 68];
    const int k0 = kx * 64, n0 = ny * 64;
#pragma unroll
    for (int i = 0; i < 4; ++i) {
      int kr = i * 16 + (tid >> 4);
      int nc = (tid & 15) * 4;
      float4 v = *(const float4*)&W[(size_t)(k0 + kr) * 256 + n0 + nc];
      t[kr * 68 + nc + 0] = v.x; t[kr * 68 + nc + 1] = v.y;
      t[kr * 68 + nc + 2] = v.z; t[kr * 68 + nc + 3] = v.w;
    }
    __syncthreads();
#pragma unroll
    for (int i = 0; i < 4; ++i) {
      int nr = i * 16 + (tid >> 4);
      int kc = (tid & 15) * 4;
#pragma unroll
      for (int j = 0; j < 4; ++j)
        dst[(size_t)(n0 + nr) * 256 + k0 + kc + j] = f2h(t[(kc + j) * 68 + nr]);
    }
  }
}

// ---------------------------------------------------------------------------
// k_mlp2: fused 2-layer MLP per 64-row tile, 256 thr / 4 waves.
//   hid = SiLU(A @ W1^T + b1) kept in LDS [64][264] fp16 (pad-264: 2-way
//   bank alias only); out = hid @ W2^T + b2 -> outB fp16 (+ outT transposed).
// Staging via global_load_lds, source-swizzled col (rule #21).
// LDS: Wst 32KB + Ast 8KB + hid 33.8KB = 74.75KB -> 2 blocks/CU.
// ---------------------------------------------------------------------------
struct MJob {
  const unsigned short* A; const unsigned short* W1; const float* b1;
  const unsigned short* W2; const float* b2;
  unsigned short* outB; unsigned short* outT;
};
struct MJobs { MJob j[3]; };

__global__ __launch_bounds__(256) void k_mlp2(MJobs jobs)
{
  __shared__ __align__(16) char Wst[32768];   // 256 n x 64 k fp16 (128B rows)
  __shared__ __align__(16) char Ast[8192];    // 64 m x 64 k
  __shared__ __align__(16) char Hst[64 * 528];// hid [64][264] fp16

  const MJob jb = jobs.j[blockIdx.y];
  const int tid  = threadIdx.x;
  const int lane = tid & 63;
  const int w    = tid >> 6;       // 0..3, n-slice
  const int rq   = lane & 15;
  const int kq   = lane >> 4;
  const int m0   = blockIdx.x * 64;
  const char* Ag  = (const char*)jb.A  + (size_t)m0 * 512;
  const char* W1g = (const char*)jb.W1;
  const char* W2g = (const char*)jb.W2;

  f32x4 acc[4][4];
#pragma unroll
  for (int mi = 0; mi < 4; ++mi)
#pragma unroll
    for (int ni = 0; ni < 4; ++ni) acc[mi][ni] = (f32x4){0.f, 0.f, 0.f, 0.f};

  // ---- layer 1 ----
  for (int kt = 0; kt < 4; ++kt) {
    __syncthreads();
#pragma unroll
    for (int i = 0; i < 2; ++i) {            // A: 512 chunks
      int c = i * 256 + tid;
      int row = c >> 3, ch = c & 7;
      int colg = (ch * 16) ^ ((row & 7) << 4);
      gll16(Ag + (size_t)row * 512 + kt * 128 + colg, Ast + i * 4096 + w * 1024);
    }
#pragma unroll
    for (int i = 0; i < 8; ++i) {            // W1: 2048 chunks
      int c = i * 256 + tid;
      int row = c >> 3, ch = c & 7;
      int colg = (ch * 16) ^ ((row & 7) << 4);
      gll16(W1g + (size_t)row * 512 + kt * 128 + colg, Wst + i * 4096 + w * 1024);
    }
    __syncthreads();
#pragma unroll
    for (int ks = 0; ks < 2; ++ks) {
      const int kb = ks * 64 + kq * 16;
      f16x8 af[4], bfr[4];
#pragma unroll
      for (int mi = 0; mi < 4; ++mi) {
        int row = mi * 16 + rq;
        af[mi] = *(const f16x8*)(Ast + row * 128 + (kb ^ ((row & 7) << 4)));
      }
#pragma unroll
      for (int ni = 0; ni < 4; ++ni) {
        int row = w * 64 + ni * 16 + rq;
        bfr[ni] = *(const f16x8*)(Wst + row * 128 + (kb ^ ((row & 7) << 4)));
      }
#pragma unroll
      for (int mi = 0; mi < 4; ++mi)
#pragma unroll
        for (int ni = 0; ni < 4; ++ni)
          acc[mi][ni] = __builtin_amdgcn_mfma_f32_16x16x32_f16(
              af[mi], bfr[ni], acc[mi][ni], 0, 0, 0);
    }
  }
  // SiLU -> hid LDS
  {
#pragma unroll
    for (int ni = 0; ni < 4; ++ni) {
      const int n = w * 64 + ni * 16 + rq;
      const float bv = jb.b1[n];
#pragma unroll
      for (int mi = 0; mi < 4; ++mi)
#pragma unroll
        for (int j = 0; j < 4; ++j) {
          float vl = acc[mi][ni][j] + bv;
          vl = vl / (1.0f + __expf(-vl));
          int m = mi * 16 + kq * 4 + j;
          *(unsigned short*)(Hst + m * 528 + n * 2) = f2h(vl);
        }
    }
  }
#pragma unroll
  for (int mi = 0; mi < 4; ++mi)
#pragma unroll
    for (int ni = 0; ni < 4; ++ni) acc[mi][ni] = (f32x4){0.f, 0.f, 0.f, 0.f};

  // ---- layer 2 (A from hid LDS) ----
  for (int kt = 0; kt < 4; ++kt) {
    __syncthreads();   // kt=0: all layer-1 reads + hid writes complete
#pragma unroll
    for (int i = 0; i < 8; ++i) {
      int c = i * 256 + tid;
      int row = c >> 3, ch = c & 7;
      int colg = (ch * 16) ^ ((row & 7) << 4);
      gll16(W2g + (size_t)row * 512 + kt * 128 + colg, Wst + i * 4096 + w * 1024);
    }
    __syncthreads();
#pragma unroll
    for (int ks = 0; ks < 2; ++ks) {
      const int kb = ks * 64 + kq * 16;
      f16x8 af[4], bfr[4];
#pragma unroll
      for (int mi = 0; mi < 4; ++mi) {
        int row = mi * 16 + rq;
        af[mi] = *(const f16x8*)(Hst + row * 528 + kt * 128 + kb);
      }
#pragma unroll
      for (int ni = 0; ni < 4; ++ni) {
        int row = w * 64 + ni * 16 + rq;
        bfr[ni] = *(const f16x8*)(Wst + row * 128 + (kb ^ ((row & 7) << 4)));
      }
#pragma unroll
      for (int mi = 0; mi < 4; ++mi)
#pragma unroll
        for (int ni = 0; ni < 4; ++ni)
          acc[mi][ni] = __builtin_amdgcn_mfma_f32_16x16x32_f16(
              af[mi], bfr[ni], acc[mi][ni], 0, 0, 0);
    }
  }

  // ---- epilogue ----
  const int bb = m0 >> 9;
  const int tbase = m0 & 511;
#pragma unroll
  for (int ni = 0; ni < 4; ++ni) {
    const int n = w * 64 + ni * 16 + rq;
    const float bv = jb.b2[n];
#pragma unroll
    for (int mi = 0; mi < 4; ++mi) {
      float vl4[4];
#pragma unroll
      for (int j = 0; j < 4; ++j) vl4[j] = acc[mi][ni][j] + bv;
#pragma unroll
      for (int j = 0; j < 4; ++j) {
        int m = m0 + mi * 16 + kq * 4 + j;
        jb.outB[(size_t)m * 256 + n] = f2h(vl4[j]);
      }
      if (jb.outT) {
        ushort4 o;
        o.x = f2h(vl4[0]); o.y = f2h(vl4[1]);
        o.z = f2h(vl4[2]); o.w = f2h(vl4[3]);
        *(ushort4*)&jb.outT[((size_t)(bb * 256 + n) << 9) +
                            tbase + mi * 16 + kq * 4] = o;
      }
    }
  }
}

// ---------------------------------------------------------------------------
// fp16 MFMA GEMM (single layer): BM=128, BN=256, BK=64, 512 thr / 8 waves.
// Runtime act; mMax early-exit; outB row-major, outE = emb-transposed
// [n][ETS] write, vxOut = fused matvec epilogue.
// ---------------------------------------------------------------------------
struct GJob {
  const unsigned short* A; const unsigned short* Wt; const float* bias;
  unsigned short* outB; unsigned short* outE;
  const float* vxW; float* vxOut;
  int act; int mMax;
};
struct GJobs { GJob j[2]; };

__global__ __launch_bounds__(512) void k_gemm(GJobs jobs)
{
  __shared__ __align__(16) char AsB[16384];   // A[128 m][64 k]
  __shared__ __align__(16) char WsB[32768];   // W[256 n][64 k]

  const GJob jb = jobs.j[blockIdx.z];
  const int m0 = blockIdx.x * 128;
  if (m0 >= jb.mMax) return;                  // block-uniform exit

  const int tid  = threadIdx.x;
  const int lane = tid & 63;
  const int w    = tid >> 6;
  const int wr   = w >> 2, wc = w & 3;
  const int rq   = lane & 15;
  const int kq   = lane >> 4;

  const char* Ag = (const char*)jb.A + (size_t)m0 * 512;
  const char* Wg = (const char*)jb.Wt;

  f32x4 acc[4][4];
#pragma unroll
  for (int mi = 0; mi < 4; ++mi)
#pragma unroll
    for (int ni = 0; ni < 4; ++ni) acc[mi][ni] = (f32x4){0.f, 0.f, 0.f, 0.f};

  for (int kt = 0; kt < 4; ++kt) {
    __syncthreads();
#pragma unroll
    for (int i = 0; i < 2; ++i) {
      int c = i * 512 + tid;
      int row = c >> 3, ch = c & 7;
      int colg = (ch * 16) ^ ((row & 7) << 4);
      gll16(Ag + (size_t)row * 512 + kt * 128 + colg, AsB + i * 8192 + w * 1024);
    }
#pragma unroll
    for (int i = 0; i < 4; ++i) {
      int c = i * 512 + tid;
      int row = c >> 3, ch = c & 7;
      int colg = (ch * 16) ^ ((row & 7) << 4);
      gll16(Wg + (size_t)row * 512 + kt * 128 + colg, WsB + i * 8192 + w * 1024);
    }
    __syncthreads();
#pragma unroll
    for (int ks = 0; ks < 2; ++ks) {
      const int kb = ks * 64 + kq * 16;
      f16x8 af[4], bfr[4];
#pragma unroll
      for (int mi = 0; mi < 4; ++mi) {
        int row = wr * 64 + mi * 16 + rq;
        af[mi] = *(const f16x8*)(AsB + row * 128 + (kb ^ ((row & 7) << 4)));
      }
#pragma unroll
      for (int ni = 0; ni < 4; ++ni) {
        int row = wc * 64 + ni * 16 + rq;
        bfr[ni] = *(const f16x8*)(WsB + row * 128 + (kb ^ ((row & 7) << 4)));
      }
#pragma unroll
      for (int mi = 0; mi < 4; ++mi)
#pragma unroll
        for (int ni = 0; ni < 4; ++ni)
          acc[mi][ni] = __builtin_amdgcn_mfma_f32_16x16x32_f16(
              af[mi], bfr[ni], acc[mi][ni], 0, 0, 0);
    }
  }

  float bv[4];
#pragma unroll
  for (int ni = 0; ni < 4; ++ni)
    bv[ni] = jb.bias[wc * 64 + ni * 16 + rq];

  float vxp_[4][4];
#pragma unroll
  for (int mi = 0; mi < 4; ++mi)
#pragma unroll
    for (int j = 0; j < 4; ++j) vxp_[mi][j] = 0.f;

#pragma unroll
  for (int mi = 0; mi < 4; ++mi) {
#pragma unroll
    for (int ni = 0; ni < 4; ++ni) {
      const int n = wc * 64 + ni * 16 + rq;
      float vl4[4];
#pragma unroll
      for (int j = 0; j < 4; ++j) {
        float vl = acc[mi][ni][j] + bv[ni];
        if (jb.act) vl = vl / (1.0f + __expf(-vl));
        vl4[j] = vl;
      }
      const int mb = m0 + wr * 64 + mi * 16 + kq * 4;
      if (jb.outB) {
#pragma unroll
        for (int j = 0; j < 4; ++j)
          jb.outB[(size_t)(mb + j) * 256 + n] = f2h(vl4[j]);
      }
      if (jb.outE) {
#pragma unroll
        for (int j = 0; j < 4; ++j)
          jb.outE[(size_t)n * ETS + mb + j] = f2h(vl4[j]);
      }
      if (jb.vxOut) {
        float wq = jb.vxW[n];
#pragma unroll
        for (int j = 0; j < 4; ++j) vxp_[mi][j] = fmaf(vl4[j], wq, vxp_[mi][j]);
      }
    }
  }

  if (jb.vxOut) {
#pragma unroll
    for (int mi = 0; mi < 4; ++mi)
#pragma unroll
      for (int j = 0; j < 4; ++j) {
        float s = vxp_[mi][j];
        s += __shfl_xor(s, 1); s += __shfl_xor(s, 2);
        s += __shfl_xor(s, 4); s += __shfl_xor(s, 8);
        if (rq == 0)
          atomicAdd(&jb.vxOut[m0 + wr * 64 + mi * 16 + kq * 4 + j], s);
      }
  }
}

// ---------------------------------------------------------------------------
// MFMA fused attention (round-12/13 kernel, unchanged).
// ---------------------------------------------------------------------------
__global__ __launch_bounds__(256, 2) void k_attn6(
    const float* __restrict__ xin, const float* __restrict__ hin,
    const unsigned short* __restrict__ qH, const unsigned short* __restrict__ kH,
    const unsigned short* __restrict__ vtH, const float* __restrict__ vxm,
    const float* __restrict__ xb2p,
    const unsigned short* __restrict__ embB, const unsigned short* __restrict__ embT,
    float* __restrict__ xout, float* __restrict__ hout)
{
  __shared__ __align__(16) char smem[70656];
  float* S  = (float*)smem;                              // [32][524]
  unsigned short* Pb = (unsigned short*)smem;            // [32][520], after S dies
  unsigned short* Pe = (unsigned short*)(smem + 33280);  // [32][584]

  const int tid  = threadIdx.x;
  const int lane = tid & 63;
  const int w    = tid >> 6;
  const int rq   = lane & 15;
  const int kq   = lane >> 4;
  const int id = blockIdx.x;
  const int t0 = ((id >> 3) & 15) * 32;
  const int b  = (id & 7) + 8 * (id >> 7);
  const int sw = w * 128;

  f16x8 q0[8], q1[8];
  {
    const size_t qo = ((size_t)(b * TS + t0 + rq) << 8) + kq * 8;
#pragma unroll
    for (int ks = 0; ks < 8; ++ks) {
      q0[ks] = *(const f16x8*)(qH + qo + ks * 32);
      q1[ks] = *(const f16x8*)(qH + qo + 4096 + ks * 32);
    }
  }

  f32x4 a0[8], a1[8];
#pragma unroll
  for (int ni = 0; ni < 8; ++ni) {
    a0[ni] = (f32x4){0.f, 0.f, 0.f, 0.f};
    a1[ni] = (f32x4){0.f, 0.f, 0.f, 0.f};
  }
  {
    const unsigned short* kp = kH + ((size_t)(b * TS + sw + rq) << 8) + kq * 8;
    f16x8 kA[8], kB[8];
#pragma unroll
    for (int ni = 0; ni < 8; ++ni) kA[ni] = *(const f16x8*)(kp + ni * 4096);
#pragma unroll
    for (int ni = 0; ni < 8; ++ni) kB[ni] = *(const f16x8*)(kp + ni * 4096 + 32);
#pragma unroll
    for (int ks = 0; ks < 8; ks += 2) {
#pragma unroll
      for (int ni = 0; ni < 8; ++ni) {
        a0[ni] = __builtin_amdgcn_mfma_f32_16x16x32_f16(q0[ks], kA[ni], a0[ni], 0, 0, 0);
        a1[ni] = __builtin_amdgcn_mfma_f32_16x16x32_f16(q1[ks], kA[ni], a1[ni], 0, 0, 0);
        if (ks + 2 < 8) kA[ni] = *(const f16x8*)(kp + ni * 4096 + (ks + 2) * 32);
      }
#pragma unroll
      for (int ni = 0; ni < 8; ++ni) {
        a0[ni] = __builtin_amdgcn_mfma_f32_16x16x32_f16(q0[ks + 1], kB[ni], a0[ni], 0, 0, 0);
        a1[ni] = __builtin_amdgcn_mfma_f32_16x16x32_f16(q1[ks + 1], kB[ni], a1[ni], 0, 0, 0);
        if (ks + 3 < 8) kB[ni] = *(const f16x8*)(kp + ni * 4096 + (ks + 3) * 32);
      }
    }
  }

  const int rbR = t0 - sw + 384;
  const unsigned short* ep = embB + ((size_t)(rbR + rq) << 8) + kq * 8;
  f16x8 eA[10], eB[10];
#pragma unroll
  for (int f = 0; f < 10; ++f) eA[f] = *(const f16x8*)(ep + f * 4096);
#pragma unroll
  for (int ni = 0; ni < 8; ++ni)
#pragma unroll
    for (int j = 0; j < 4; ++j) {
      S[(kq * 4 + j) * 524 + sw + ni * 16 + rq]        = a0[ni][j];
      S[(16 + kq * 4 + j) * 524 + sw + ni * 16 + rq]   = a1[ni][j];
    }
#pragma unroll
  for (int f = 0; f < 10; ++f) eB[f] = *(const f16x8*)(ep + f * 4096 + 32);

  f32x4 r0[9], r1[9];
#pragma unroll
  for (int ni = 0; ni < 9; ++ni) {
    r0[ni] = (f32x4){0.f, 0.f, 0.f, 0.f};
    r1[ni] = (f32x4){0.f, 0.f, 0.f, 0.f};
  }
#pragma unroll
  for (int ks = 0; ks < 8; ks += 2) {
#pragma unroll
    for (int f = 0; f < 10; ++f) {
      if (f < 9) r0[f] = __builtin_amdgcn_mfma_f32_16x16x32_f16(q0[ks], eA[f], r0[f], 0, 0, 0);
      if (f > 0) r1[f - 1] = __builtin_amdgcn_mfma_f32_16x16x32_f16(q1[ks], eA[f], r1[f - 1], 0, 0, 0);
      if (ks + 2 < 8) eA[f] = *(const f16x8*)(ep + f * 4096 + (ks + 2) * 32);
    }
#pragma unroll
    for (int f = 0; f < 10; ++f) {
      if (f < 9) r0[f] = __builtin_amdgcn_mfma_f32_16x16x32_f16(q0[ks + 1], eB[f], r0[f], 0, 0, 0);
      if (f > 0) r1[f - 1] = __builtin_amdgcn_mfma_f32_16x16x32_f16(q1[ks + 1], eB[f], r1[f - 1], 0, 0, 0);
      if (ks + 3 < 8) eB[f] = *(const f16x8*)(ep + f * 4096 + (ks + 3) * 32);
    }
  }

  asm volatile("s_waitcnt lgkmcnt(0)" ::: "memory");
  __builtin_amdgcn_sched_barrier(0);
#pragma unroll
  for (int ni = 0; ni < 9; ++ni)
#pragma unroll
    for (int j = 0; j < 4; ++j) {
      int tp  = kq * 4 + j;
      int slw = tp + 127 - (ni * 16 + rq);
      if (slw >= 0 && slw < 128) {
        S[tp * 524 + sw + slw]        += r0[ni][j];
        S[(16 + tp) * 524 + sw + slw] += r1[ni][j];
      }
    }
  __syncthreads();

  const int row16 = tid >> 4, tx = tid & 15;
  float p0[32], p1[32];
  float invl0, invl1;
#pragma unroll
  for (int pass = 0; pass < 2; ++pass) {
    float* pp = pass ? p1 : p0;
    const float* Srow = S + (pass * 16 + row16) * 524 + tx * 4;
    float mx = -3.0e38f, l = 0.f;
#pragma unroll
    for (int i = 0; i < 8; ++i) {
      float4 v = *(const float4*)(Srow + i * 64);
      pp[4*i+0] = v.x; pp[4*i+1] = v.y; pp[4*i+2] = v.z; pp[4*i+3] = v.w;
    }
#pragma unroll
    for (int i = 0; i < 32; ++i) mx = fmaxf(mx, pp[i]);
    mx = fmaxf(mx, __shfl_xor(mx, 1)); mx = fmaxf(mx, __shfl_xor(mx, 2));
    mx = fmaxf(mx, __shfl_xor(mx, 4)); mx = fmaxf(mx, __shfl_xor(mx, 8));
#pragma unroll
    for (int i = 0; i < 32; ++i) { pp[i] = __expf(pp[i] - mx); l += pp[i]; }
    l += __shfl_xor(l, 1); l += __shfl_xor(l, 2);
    l += __shfl_xor(l, 4); l += __shfl_xor(l, 8);
    if (pass) invl1 = 1.0f / l; else invl0 = 1.0f / l;
  }

  {
    const float xb2c = xb2p[0];
    const float* vxp = vxm + b * TS;
    const float* xp  = xin + (size_t)b * 3 * TS;
    float w0s = 0.f, xa00 = 0.f, xa01 = 0.f, xa02 = 0.f;
    float w1s = 0.f, xa10 = 0.f, xa11 = 0.f, xa12 = 0.f;
#pragma unroll
    for (int i = 0; i < 8; ++i) {
      int s = i * 64 + tx * 4;
      float4 vv = *(const float4*)(vxp + s);
      float4 x0 = *(const float4*)(xp + s);
      float4 x1 = *(const float4*)(xp + TS + s);
      float4 x2 = *(const float4*)(xp + 2 * TS + s);
      float vb0 = vv.x + xb2c, vb1 = vv.y + xb2c, vb2 = vv.z + xb2c, vb3 = vv.w + xb2c;
      float wv;
      wv = p0[4*i+0] * vb0; w0s += wv; xa00 = fmaf(wv, x0.x, xa00); xa01 = fmaf(wv, x1.x, xa01); xa02 = fmaf(wv, x2.x, xa02);
      wv = p0[4*i+1] * vb1; w0s += wv; xa00 = fmaf(wv, x0.y, xa00); xa01 = fmaf(wv, x1.y, xa01); xa02 = fmaf(wv, x2.y, xa02);
      wv = p0[4*i+2] * vb2; w0s += wv; xa00 = fmaf(wv, x0.z, xa00); xa01 = fmaf(wv, x1.z, xa01); xa02 = fmaf(wv, x2.z, xa02);
      wv = p0[4*i+3] * vb3; w0s += wv; xa00 = fmaf(wv, x0.w, xa00); xa01 = fmaf(wv, x1.w, xa01); xa02 = fmaf(wv, x2.w, xa02);
      wv = p1[4*i+0] * vb0; w1s += wv; xa10 = fmaf(wv, x0.x, xa10); xa11 = fmaf(wv, x1.x, xa11); xa12 = fmaf(wv, x2.x, xa12);
      wv = p1[4*i+1] * vb1; w1s += wv; xa10 = fmaf(wv, x0.y, xa10); xa11 = fmaf(wv, x1.y, xa11); xa12 = fmaf(wv, x2.y, xa12);
      wv = p1[4*i+2] * vb2; w1s += wv; xa10 = fmaf(wv, x0.z, xa10); xa11 = fmaf(wv, x1.z, xa11); xa12 = fmaf(wv, x2.z, xa12);
      wv = p1[4*i+3] * vb3; w1s += wv; xa10 = fmaf(wv, x0.w, xa10); xa11 = fmaf(wv, x1.w, xa11); xa12 = fmaf(wv, x2.w, xa12);
    }
#pragma unroll
    for (int m = 1; m < 16; m <<= 1) {
      w0s += __shfl_xor(w0s, m); xa00 += __shfl_xor(xa00, m);
      xa01 += __shfl_xor(xa01, m); xa02 += __shfl_xor(xa02, m);
      w1s += __shfl_xor(w1s, m); xa10 += __shfl_xor(xa10, m);
      xa11 += __shfl_xor(xa11, m); xa12 += __shfl_xor(xa12, m);
    }
    if (tx == 0) {
      int ta = t0 + row16, tb2 = t0 + 16 + row16;
      float wsa = w0s * invl0, wsb = w1s * invl1;
      xout[(b * 3 + 0) * TS + ta] = xp[ta]          * (1.0f + wsa) - xa00 * invl0;
      xout[(b * 3 + 1) * TS + ta] = xp[TS + ta]     * (1.0f + wsa) - xa01 * invl0;
      xout[(b * 3 + 2) * TS + ta] = xp[2 * TS + ta] * (1.0f + wsa) - xa02 * invl0;
      xout[(b * 3 + 0) * TS + tb2] = xp[tb2]          * (1.0f + wsb) - xa10 * invl1;
      xout[(b * 3 + 1) * TS + tb2] = xp[TS + tb2]     * (1.0f + wsb) - xa11 * invl1;
      xout[(b * 3 + 2) * TS + tb2] = xp[2 * TS + tb2] * (1.0f + wsb) - xa12 * invl1;
    }
  }
  __syncthreads();

  {
    unsigned int* pz = (unsigned int*)Pe;
    for (int i = tid; i < 9344; i += 256) pz[i] = 0u;
  }
  __syncthreads();

#pragma unroll
  for (int pass = 0; pass < 2; ++pass) {
    const float* pp = pass ? p1 : p0;
    const float il = pass ? invl1 : invl0;
    const int row = pass * 16 + row16;
    unsigned short* pbrow = Pb + row * 520 + tx * 4;
    unsigned short* perow = Pe + row * 584 + row + 511;
#pragma unroll
    for (int i = 0; i < 8; ++i) {
      int s = i * 64 + tx * 4;
      ushort4 pu;
      pu.x = f2h(pp[4*i+0] * il); pu.y = f2h(pp[4*i+1] * il);
      pu.z = f2h(pp[4*i+2] * il); pu.w = f2h(pp[4*i+3] * il);
      *(ushort4*)(pbrow + i * 64) = pu;
      perow[-(s + 0)] = pu.x; perow[-(s + 1)] = pu.y;
      perow[-(s + 2)] = pu.z; perow[-(s + 3)] = pu.w;
    }
  }
  __syncthreads();

  const int n0 = w * 64;
  f32x4 o0[4], o1[4];
#pragma unroll
  for (int ni = 0; ni < 4; ++ni) {
    o0[ni] = (f32x4){0.f, 0.f, 0.f, 0.f};
    o1[ni] = (f32x4){0.f, 0.f, 0.f, 0.f};
  }
  {
    const unsigned short* pb0 = Pb + rq * 520 + kq * 8;
    const unsigned short* pb1 = Pb + (16 + rq) * 520 + kq * 8;
    const unsigned short* pe0 = Pe + rq * 584 + kq * 8;
    const unsigned short* pe1 = Pe + (16 + rq) * 584 + kq * 8;
    const unsigned short* vtp = vtH + ((size_t)(b * 256 + n0 + rq) << 9) + kq * 8;
    const unsigned short* etp = embT + (size_t)(n0 + rq) * ETS + t0 + kq * 8;
    f16x8 vA[4], vB[4], gA[4], gB[4];
#pragma unroll
    for (int ni = 0; ni < 4; ++ni) {
      vA[ni] = *(const f16x8*)(vtp + ni * 8192);
      gA[ni] = *(const f16x8*)(etp + ni * 16 * ETS);
      vB[ni] = *(const f16x8*)(vtp + ni * 8192 + 32);
      gB[ni] = *(const f16x8*)(etp + ni * 16 * ETS + 32);
    }
#pragma unroll
    for (int kk = 0; kk < 16; kk += 2) {
      f16x8 pa0 = *(const f16x8*)(pb0 + kk * 32);
      f16x8 pa1 = *(const f16x8*)(pb1 + kk * 32);
#pragma unroll
      for (int ni = 0; ni < 4; ++ni) {
        o0[ni] = __builtin_amdgcn_mfma_f32_16x16x32_f16(pa0, vA[ni], o0[ni], 0, 0, 0);
        o1[ni] = __builtin_amdgcn_mfma_f32_16x16x32_f16(pa1, vA[ni], o1[ni], 0, 0, 0);
        if (kk + 2 < 16) vA[ni] = *(const f16x8*)(vtp + ni * 8192 + (kk + 2) * 32);
      }
      f16x8 pe0f = *(const f16x8*)(pe0 + kk * 32);
      f16x8 pe1f = *(const f16x8*)(pe1 + kk * 32);
#pragma unroll
      for (int ni = 0; ni < 4; ++ni) {
        o0[ni] = __builtin_amdgcn_mfma_f32_16x16x32_f16(pe0f, gA[ni], o0[ni], 0, 0, 0);
        o1[ni] = __builtin_amdgcn_mfma_f32_16x16x32_f16(pe1f, gA[ni], o1[ni], 0, 0, 0);
        if (kk + 2 < 17) gA[ni] = *(const f16x8*)(etp + ni * 16 * ETS + (kk + 2) * 32);
      }
      f16x8 pc0 = *(const f16x8*)(pb0 + (kk + 1) * 32);
      f16x8 pc1 = *(const f16x8*)(pb1 + (kk + 1) * 32);
#pragma unroll
      for (int ni = 0; ni < 4; ++ni) {
        o0[ni] = __builtin_amdgcn_mfma_f32_16x16x32_f16(pc0, vB[ni], o0[ni], 0, 0, 0);
        o1[ni] = __builtin_amdgcn_mfma_f32_16x16x32_f16(pc1, vB[ni], o1[ni], 0, 0, 0);
        if (kk + 3 < 16) vB[ni] = *(const f16x8*)(vtp + ni * 8192 + (kk + 3) * 32);
      }
      f16x8 pd0 = *(const f16x8*)(pe0 + (kk + 1) * 32);
      f16x8 pd1 = *(const f16x8*)(pe1 + (kk + 1) * 32);
#pragma unroll
      for (int ni = 0; ni < 4; ++ni) {
        o0[ni] = __builtin_amdgcn_mfma_f32_16x16x32_f16(pd0, gB[ni], o0[ni], 0, 0, 0);
        o1[ni] = __builtin_amdgcn_mfma_f32_16x16x32_f16(pd1, gB[ni], o1[ni], 0, 0, 0);
        if (kk + 3 < 17) gB[ni] = *(const f16x8*)(etp + ni * 16 * ETS + (kk + 3) * 32);
      }
    }
    f16x8 pt0 = *(const f16x8*)(pe0 + 16 * 32);
    f16x8 pt1 = *(const f16x8*)(pe1 + 16 * 32);
#pragma unroll
    for (int ni = 0; ni < 4; ++ni) {
      o0[ni] = __builtin_amdgcn_mfma_f32_16x16x32_f16(pt0, gA[ni], o0[ni], 0, 0, 0);
      o1[ni] = __builtin_amdgcn_mfma_f32_16x16x32_f16(pt1, gA[ni], o1[ni], 0, 0, 0);
    }
  }

  {
#pragma unroll
    for (int ni = 0; ni < 4; ++ni) {
      int hh = n0 + ni * 16 + rq;
      size_t base = (((size_t)(b * 256 + hh)) << 9) + t0 + kq * 4;
      float4 hv0 = *(const float4*)(hin + base);
      float4 ov0;
      ov0.x = hv0.x + o0[ni][0];
      ov0.y = hv0.y + o0[ni][1];
      ov0.z = hv0.z + o0[ni][2];
      ov0.w = hv0.w + o0[ni][3];
      *(float4*)(hout + base) = ov0;
      float4 hv1 = *(const float4*)(hin + base + 16);
      float4 ov1;
      ov1.x = hv1.x + o1[ni][0];
      ov1.y = hv1.y + o1[ni][1];
      ov1.z = hv1.z + o1[ni][2];
      ov1.w = hv1.w + o1[ni][3];
      *(float4*)(hout + base + 16) = ov1;
    }
  }
}

// ---------------------------------------------------------------------------
extern "C" void kernel_launch(void* const* d_in, const int* in_sizes, int n_in,
                              void* d_out, int out_size, void* d_ws, size_t ws_size,
                              hipStream_t stream)
{
  const float* x   = (const float*)d_in[0];
  const float* h   = (const float*)d_in[1];
  const float* qW1 = (const float*)d_in[2];
  const float* qb1 = (const float*)d_in[3];
  const float* qW2 = (const float*)d_in[4];
  const float* qb2 = (const float*)d_in[5];
  const float* kW1 = (const float*)d_in[6];
  const float* kb1 = (const float*)d_in[7];
  const float* kW2 = (const float*)d_in[8];
  const float* kb2 = (const float*)d_in[9];
  const float* vW1 = (const float*)d_in[10];
  const float* vb1 = (const float*)d_in[11];
  const float* vW2 = (const float*)d_in[12];
  const float* vb2 = (const float*)d_in[13];
  const float* xW1 = (const float*)d_in[14];
  const float* xb1 = (const float*)d_in[15];
  const float* xW2 = (const float*)d_in[16];
  const float* xb2 = (const float*)d_in[17];
  const float* teW = (const float*)d_in[18];
  const float* teb = (const float*)d_in[19];

  // ws layout (fp16 except vx) ~66 MB
  unsigned short* cur = (unsigned short*)d_ws;
  unsigned short* embB = cur; cur += 1024 * 256;
  unsigned short* embT = cur; cur += 256 * ETS;
  unsigned short* SC   = cur; cur += 1024 * 256;
  unsigned short* hmH  = cur; cur += (size_t)24576 * 256;
  unsigned short* WtH  = cur; cur += 8 * 65536;
  unsigned short* qHp  = cur; cur += (size_t)24576 * 256;
  unsigned short* kHp  = cur; cur += (size_t)24576 * 256;
  unsigned short* vHp  = cur; cur += (size_t)24576 * 256;
  unsigned short* vtH  = cur; cur += (size_t)24576 * 256;
  float* vx = (float*)cur;                                // 24576 f32

  float* xout = (float*)d_out;                // [48,3,512]
  float* hout = xout + NB * 3 * TS;           // [48,256,512]

  // 1) all preps in one launch (sincos | h->hmH+vx | 8x weight transpose)
  k_prep<<<1792, 256, 0, stream>>>(h, hmH, vx,
                                   qW1, qW2, kW1, kW2, vW1, vW2, xW1, teW,
                                   WtH, SC);

  // 2) fused 2-layer MLPs: q, k, v (v also writes Vt transposed)
  {
    MJobs jm{{{hmH, WtH + 0 * 65536, qb1, WtH + 1 * 65536, qb2, qHp, nullptr},
              {hmH, WtH + 2 * 65536, kb1, WtH + 3 * 65536, kb2, kHp, nullptr},
              {hmH, WtH + 4 * 65536, vb1, WtH + 5 * 65536, vb2, vHp, vtH}}};
    k_mlp2<<<dim3(384, 3), 256, 0, stream>>>(jm);
  }

  // 3) emb GEMM (SC @ teW^T -> embB + embT) and x-MLP layer1+vx, one launch
  {
    GJobs jg{{{SC,  WtH + 7 * 65536, teb, embB, embT, nullptr, nullptr, 0, 1024},
              {vHp, WtH + 6 * 65536, xb1, nullptr, nullptr, xW2, vx, 1, 24576}}};
    k_gemm<<<dim3(192, 1, 2), 512, 0, stream>>>(jg);
  }

  // 4) fused attention (unchanged)
  k_attn6<<<768, 256, 0, stream>>>(x, h, qHp, kHp, vtH, vx, xb2,
                                   embB, embT, xout, hout);
}

// Round 16
// 177.025 us; speedup vs baseline: 1.1488x; 1.0747x over previous
//
#include <hip/hip_runtime.h>
#include <math.h>

// Problem constants
#define NB 48      // batch*nodes
#define HD 256     // hidden
#define TS 512     // timesteps
// 2T-1 = 1023 relative positions; embT padded to 1056 cols

typedef _Float16 f16x8 __attribute__((ext_vector_type(8)));
typedef float    f32x4 __attribute__((ext_vector_type(4)));

__device__ inline unsigned short f2h(float f) {       // f32 -> fp16 bits (RNE)
  union { _Float16 h; unsigned short u; } v; v.h = (_Float16)f; return v.u;
}
__device__ inline float h2f(unsigned short u) {
  union { unsigned short u; _Float16 h; } v; v.u = u; return (float)v.h;
}

#define ETS 1056   // embT row stride (cols 1023..1055 never read; finite fill)

// async global->LDS, 16B per lane (GEMM staging)
__device__ __forceinline__ void gll16(const void* g, void* l) {
  __builtin_amdgcn_global_load_lds(
      (const __attribute__((address_space(1))) unsigned int*)g,
      (__attribute__((address_space(3))) unsigned int*)l, 16, 0, 0);
}

// ---------------------------------------------------------------------------
// k_prep: 1D grid 1792 blocks x 256 thr
//   [0,128)     sincos table SC[1024][256] fp16 (row 1023 = 0)
//   [128,1664)  h [48,256,512] f32 -> hmH [24576][256] fp16 (+ zero vx)
//   [1664,1792) 8 weights f32 [256][256] -> fp16 transposed [N][K]
// ---------------------------------------------------------------------------
__global__ __launch_bounds__(256) void k_prep(
    const float* __restrict__ h, unsigned short* __restrict__ hmH,
    float* __restrict__ vxZ,
    const float* __restrict__ w0, const float* __restrict__ w1,
    const float* __restrict__ w2, const float* __restrict__ w3,
    const float* __restrict__ w4, const float* __restrict__ w5,
    const float* __restrict__ w6, const float* __restrict__ w7,
    unsigned short* __restrict__ WtH, unsigned short* __restrict__ SC)
{
  const int gid = blockIdx.x;
  const int tid = threadIdx.x;

  if (gid < 128) {                       // ---- sincos table ----
    const int cf = tid & 127, half = tid >> 7;
    const float f = expf((float)cf * (-9.210340371976184f / 127.0f));
#pragma unroll
    for (int rr = 0; rr < 8; ++rr) {
      int r = gid * 8 + rr;
      float ang = (float)(r - (TS - 1)) * f;
      float val = (r == 1023) ? 0.0f : (half ? cosf(ang) : sinf(ang));
      SC[r * 256 + tid] = f2h(val);
    }
    return;
  }
  if (gid < 1664) {                      // ---- h transpose -> hmH ----
    const int idx = gid - 128;
    const int bx = idx & 3, by = (idx >> 2) & 7, bz = idx >> 5;
    __shared__ float t[32 * 132];
    const int t0 = bx * 128, c0 = by * 32, b = bz;
    if (by == 0 && bz == 0) {            // zero vx (4 blocks x 256 x 24)
      float4* vz = (float4*)(vxZ + ((size_t)bx * 256 + tid) * 24);
#pragma unroll
      for (int i = 0; i < 6; ++i) vz[i] = make_float4(0.f, 0.f, 0.f, 0.f);
    }
#pragma unroll
    for (int i = 0; i < 4; ++i) {
      int cl = i * 8 + (tid >> 5);
      int t4 = (tid & 31) * 4;
      float4 v = *(const float4*)&h[((size_t)b * 256 + c0 + cl) * 512 + t0 + t4];
      t[cl * 132 + t4 + 0] = v.x; t[cl * 132 + t4 + 1] = v.y;
      t[cl * 132 + t4 + 2] = v.z; t[cl * 132 + t4 + 3] = v.w;
    }
    __syncthreads();
#pragma unroll
    for (int i = 0; i < 16; ++i) {
      int tl = i * 8 + (tid >> 5);
      int cl = tid & 31;
      hmH[((size_t)b * 512 + t0 + tl) * 256 + c0 + cl] = f2h(t[cl * 132 + tl]);
    }
    return;
  }
  {                                      // ---- weight transpose x8 ----
    const int idx = gid - 1664;
    const int kx = idx & 3, ny = (idx >> 2) & 3, mat = idx >> 4;
    const float* W = (mat == 0) ? w0 : (mat == 1) ? w1 : (mat == 2) ? w2 :
                     (mat == 3) ? w3 : (mat == 4) ? w4 : (mat == 5) ? w5 :
                     (mat == 6) ? w6 : w7;
    unsigned short* dst = WtH + (size_t)mat * 65536;
    __shared__ float t[64 * 68];
    const int k0 = kx * 64, n0 = ny * 64;
#pragma unroll
    for (int i = 0; i < 4; ++i) {
      int kr = i * 16 + (tid >> 4);
      int nc = (tid & 15) * 4;
      float4 v = *(const float4*)&W[(size_t)(k0 + kr) * 256 + n0 + nc];
      t[kr * 68 + nc + 0] = v.x; t[kr * 68 + nc + 1] = v.y;
      t[kr * 68 + nc + 2] = v.z; t[kr * 68 + nc + 3] = v.w;
    }
    __syncthreads();
#pragma unroll
    for (int i = 0; i < 4; ++i) {
      int nr = i * 16 + (tid >> 4);
      int kc = (tid & 15) * 4;
#pragma unroll
      for (int j = 0; j < 4; ++j)
        dst[(size_t)(n0 + nr) * 256 + k0 + kc + j] = f2h(t[(kc + j) * 68 + nr]);
    }
  }
}

// ---------------------------------------------------------------------------
// k_mlp2: fused 2-layer MLP per 64-row tile, 256 thr / 4 waves.
//   hid = SiLU(A @ W1^T + b1) kept in LDS [64][264] fp16 (pad-264: 2-way
//   bank alias only); out = hid @ W2^T + b2 -> outB fp16 (+ outT transposed).
// Staging via global_load_lds, source-swizzled col (rule #21).
// LDS: Wst 32KB + Ast 8KB + hid 33.8KB = 74.75KB -> 2 blocks/CU.
// ---------------------------------------------------------------------------
struct MJob {
  const unsigned short* A; const unsigned short* W1; const float* b1;
  const unsigned short* W2; const float* b2;
  unsigned short* outB; unsigned short* outT;
};
struct MJobs { MJob j[3]; };

__global__ __launch_bounds__(256) void k_mlp2(MJobs jobs)
{
  __shared__ __align__(16) char Wst[32768];   // 256 n x 64 k fp16 (128B rows)
  __shared__ __align__(16) char Ast[8192];    // 64 m x 64 k
  __shared__ __align__(16) char Hst[64 * 528];// hid [64][264] fp16

  const MJob jb = jobs.j[blockIdx.y];
  const int tid  = threadIdx.x;
  const int lane = tid & 63;
  const int w    = tid >> 6;       // 0..3, n-slice
  const int rq   = lane & 15;
  const int kq   = lane >> 4;
  const int m0   = blockIdx.x * 64;
  const char* Ag  = (const char*)jb.A  + (size_t)m0 * 512;
  const char* W1g = (const char*)jb.W1;
  const char* W2g = (const char*)jb.W2;

  f32x4 acc[4][4];
#pragma unroll
  for (int mi = 0; mi < 4; ++mi)
#pragma unroll
    for (int ni = 0; ni < 4; ++ni) acc[mi][ni] = (f32x4){0.f, 0.f, 0.f, 0.f};

  // ---- layer 1 ----
  for (int kt = 0; kt < 4; ++kt) {
    __syncthreads();
#pragma unroll
    for (int i = 0; i < 2; ++i) {            // A: 512 chunks
      int c = i * 256 + tid;
      int row = c >> 3, ch = c & 7;
      int colg = (ch * 16) ^ ((row & 7) << 4);
      gll16(Ag + (size_t)row * 512 + kt * 128 + colg, Ast + i * 4096 + w * 1024);
    }
#pragma unroll
    for (int i = 0; i < 8; ++i) {            // W1: 2048 chunks
      int c = i * 256 + tid;
      int row = c >> 3, ch = c & 7;
      int colg = (ch * 16) ^ ((row & 7) << 4);
      gll16(W1g + (size_t)row * 512 + kt * 128 + colg, Wst + i * 4096 + w * 1024);
    }
    __syncthreads();
#pragma unroll
    for (int ks = 0; ks < 2; ++ks) {
      const int kb = ks * 64 + kq * 16;
      f16x8 af[4], bfr[4];
#pragma unroll
      for (int mi = 0; mi < 4; ++mi) {
        int row = mi * 16 + rq;
        af[mi] = *(const f16x8*)(Ast + row * 128 + (kb ^ ((row & 7) << 4)));
      }
#pragma unroll
      for (int ni = 0; ni < 4; ++ni) {
        int row = w * 64 + ni * 16 + rq;
        bfr[ni] = *(const f16x8*)(Wst + row * 128 + (kb ^ ((row & 7) << 4)));
      }
#pragma unroll
      for (int mi = 0; mi < 4; ++mi)
#pragma unroll
        for (int ni = 0; ni < 4; ++ni)
          acc[mi][ni] = __builtin_amdgcn_mfma_f32_16x16x32_f16(
              af[mi], bfr[ni], acc[mi][ni], 0, 0, 0);
    }
  }
  // SiLU -> hid LDS
  {
#pragma unroll
    for (int ni = 0; ni < 4; ++ni) {
      const int n = w * 64 + ni * 16 + rq;
      const float bv = jb.b1[n];
#pragma unroll
      for (int mi = 0; mi < 4; ++mi)
#pragma unroll
        for (int j = 0; j < 4; ++j) {
          float vl = acc[mi][ni][j] + bv;
          vl = vl / (1.0f + __expf(-vl));
          int m = mi * 16 + kq * 4 + j;
          *(unsigned short*)(Hst + m * 528 + n * 2) = f2h(vl);
        }
    }
  }
#pragma unroll
  for (int mi = 0; mi < 4; ++mi)
#pragma unroll
    for (int ni = 0; ni < 4; ++ni) acc[mi][ni] = (f32x4){0.f, 0.f, 0.f, 0.f};

  // ---- layer 2 (A from hid LDS) ----
  for (int kt = 0; kt < 4; ++kt) {
    __syncthreads();   // kt=0: all layer-1 reads + hid writes complete
#pragma unroll
    for (int i = 0; i < 8; ++i) {
      int c = i * 256 + tid;
      int row = c >> 3, ch = c & 7;
      int colg = (ch * 16) ^ ((row & 7) << 4);
      gll16(W2g + (size_t)row * 512 + kt * 128 + colg, Wst + i * 4096 + w * 1024);
    }
    __syncthreads();
#pragma unroll
    for (int ks = 0; ks < 2; ++ks) {
      const int kb = ks * 64 + kq * 16;
      f16x8 af[4], bfr[4];
#pragma unroll
      for (int mi = 0; mi < 4; ++mi) {
        int row = mi * 16 + rq;
        af[mi] = *(const f16x8*)(Hst + row * 528 + kt * 128 + kb);
      }
#pragma unroll
      for (int ni = 0; ni < 4; ++ni) {
        int row = w * 64 + ni * 16 + rq;
        bfr[ni] = *(const f16x8*)(Wst + row * 128 + (kb ^ ((row & 7) << 4)));
      }
#pragma unroll
      for (int mi = 0; mi < 4; ++mi)
#pragma unroll
        for (int ni = 0; ni < 4; ++ni)
          acc[mi][ni] = __builtin_amdgcn_mfma_f32_16x16x32_f16(
              af[mi], bfr[ni], acc[mi][ni], 0, 0, 0);
    }
  }

  // ---- epilogue ----
  const int bb = m0 >> 9;
  const int tbase = m0 & 511;
#pragma unroll
  for (int ni = 0; ni < 4; ++ni) {
    const int n = w * 64 + ni * 16 + rq;
    const float bv = jb.b2[n];
#pragma unroll
    for (int mi = 0; mi < 4; ++mi) {
      float vl4[4];
#pragma unroll
      for (int j = 0; j < 4; ++j) vl4[j] = acc[mi][ni][j] + bv;
#pragma unroll
      for (int j = 0; j < 4; ++j) {
        int m = m0 + mi * 16 + kq * 4 + j;
        jb.outB[(size_t)m * 256 + n] = f2h(vl4[j]);
      }
      if (jb.outT) {
        ushort4 o;
        o.x = f2h(vl4[0]); o.y = f2h(vl4[1]);
        o.z = f2h(vl4[2]); o.w = f2h(vl4[3]);
        *(ushort4*)&jb.outT[((size_t)(bb * 256 + n) << 9) +
                            tbase + mi * 16 + kq * 4] = o;
      }
    }
  }
}

// ---------------------------------------------------------------------------
// fp16 MFMA GEMM (single layer): BM=128, BN=256, BK=64, 512 thr / 8 waves.
// Runtime act; mMax early-exit; outB row-major, outE = emb-transposed
// [n][ETS] write, vxOut = fused matvec epilogue.
// ---------------------------------------------------------------------------
struct GJob {
  const unsigned short* A; const unsigned short* Wt; const float* bias;
  unsigned short* outB; unsigned short* outE;
  const float* vxW; float* vxOut;
  int act; int mMax;
};
struct GJobs { GJob j[2]; };

__global__ __launch_bounds__(512) void k_gemm(GJobs jobs)
{
  __shared__ __align__(16) char AsB[16384];   // A[128 m][64 k]
  __shared__ __align__(16) char WsB[32768];   // W[256 n][64 k]

  const GJob jb = jobs.j[blockIdx.z];
  const int m0 = blockIdx.x * 128;
  if (m0 >= jb.mMax) return;                  // block-uniform exit

  const int tid  = threadIdx.x;
  const int lane = tid & 63;
  const int w    = tid >> 6;
  const int wr   = w >> 2, wc = w & 3;
  const int rq   = lane & 15;
  const int kq   = lane >> 4;

  const char* Ag = (const char*)jb.A + (size_t)m0 * 512;
  const char* Wg = (const char*)jb.Wt;

  f32x4 acc[4][4];
#pragma unroll
  for (int mi = 0; mi < 4; ++mi)
#pragma unroll
    for (int ni = 0; ni < 4; ++ni) acc[mi][ni] = (f32x4){0.f, 0.f, 0.f, 0.f};

  for (int kt = 0; kt < 4; ++kt) {
    __syncthreads();
#pragma unroll
    for (int i = 0; i < 2; ++i) {
      int c = i * 512 + tid;
      int row = c >> 3, ch = c & 7;
      int colg = (ch * 16) ^ ((row & 7) << 4);
      gll16(Ag + (size_t)row * 512 + kt * 128 + colg, AsB + i * 8192 + w * 1024);
    }
#pragma unroll
    for (int i = 0; i < 4; ++i) {
      int c = i * 512 + tid;
      int row = c >> 3, ch = c & 7;
      int colg = (ch * 16) ^ ((row & 7) << 4);
      gll16(Wg + (size_t)row * 512 + kt * 128 + colg, WsB + i * 8192 + w * 1024);
    }
    __syncthreads();
#pragma unroll
    for (int ks = 0; ks < 2; ++ks) {
      const int kb = ks * 64 + kq * 16;
      f16x8 af[4], bfr[4];
#pragma unroll
      for (int mi = 0; mi < 4; ++mi) {
        int row = wr * 64 + mi * 16 + rq;
        af[mi] = *(const f16x8*)(AsB + row * 128 + (kb ^ ((row & 7) << 4)));
      }
#pragma unroll
      for (int ni = 0; ni < 4; ++ni) {
        int row = wc * 64 + ni * 16 + rq;
        bfr[ni] = *(const f16x8*)(WsB + row * 128 + (kb ^ ((row & 7) << 4)));
      }
#pragma unroll
      for (int mi = 0; mi < 4; ++mi)
#pragma unroll
        for (int ni = 0; ni < 4; ++ni)
          acc[mi][ni] = __builtin_amdgcn_mfma_f32_16x16x32_f16(
              af[mi], bfr[ni], acc[mi][ni], 0, 0, 0);
    }
  }

  float bv[4];
#pragma unroll
  for (int ni = 0; ni < 4; ++ni)
    bv[ni] = jb.bias[wc * 64 + ni * 16 + rq];

  float vxp_[4][4];
#pragma unroll
  for (int mi = 0; mi < 4; ++mi)
#pragma unroll
    for (int j = 0; j < 4; ++j) vxp_[mi][j] = 0.f;

#pragma unroll
  for (int mi = 0; mi < 4; ++mi) {
#pragma unroll
    for (int ni = 0; ni < 4; ++ni) {
      const int n = wc * 64 + ni * 16 + rq;
      float vl4[4];
#pragma unroll
      for (int j = 0; j < 4; ++j) {
        float vl = acc[mi][ni][j] + bv[ni];
        if (jb.act) vl = vl / (1.0f + __expf(-vl));
        vl4[j] = vl;
      }
      const int mb = m0 + wr * 64 + mi * 16 + kq * 4;
      if (jb.outB) {
#pragma unroll
        for (int j = 0; j < 4; ++j)
          jb.outB[(size_t)(mb + j) * 256 + n] = f2h(vl4[j]);
      }
      if (jb.outE) {
#pragma unroll
        for (int j = 0; j < 4; ++j)
          jb.outE[(size_t)n * ETS + mb + j] = f2h(vl4[j]);
      }
      if (jb.vxOut) {
        float wq = jb.vxW[n];
#pragma unroll
        for (int j = 0; j < 4; ++j) vxp_[mi][j] = fmaf(vl4[j], wq, vxp_[mi][j]);
      }
    }
  }

  if (jb.vxOut) {
#pragma unroll
    for (int mi = 0; mi < 4; ++mi)
#pragma unroll
      for (int j = 0; j < 4; ++j) {
        float s = vxp_[mi][j];
        s += __shfl_xor(s, 1); s += __shfl_xor(s, 2);
        s += __shfl_xor(s, 4); s += __shfl_xor(s, 8);
        if (rq == 0)
          atomicAdd(&jb.vxOut[m0 + wr * 64 + mi * 16 + kq * 4 + j], s);
      }
  }
}

// ---------------------------------------------------------------------------
// MFMA fused attention: round-13 structure + (a) s_setprio(1) around MFMA
// clusters (T5: waves drift to different phases in the barrier-free stream
// sections -> scheduler favors the MFMA-issuing wave), (b) phase-2 Vt/embT
// initial fragments issued BEFORE the B2..B3 barrier chain (T14 issue-early;
// loads have no Pb/Pe dependence; sched_barrier pins them).
// ---------------------------------------------------------------------------
__global__ __launch_bounds__(256, 2) void k_attn6(
    const float* __restrict__ xin, const float* __restrict__ hin,
    const unsigned short* __restrict__ qH, const unsigned short* __restrict__ kH,
    const unsigned short* __restrict__ vtH, const float* __restrict__ vxm,
    const float* __restrict__ xb2p,
    const unsigned short* __restrict__ embB, const unsigned short* __restrict__ embT,
    float* __restrict__ xout, float* __restrict__ hout)
{
  __shared__ __align__(16) char smem[70656];
  float* S  = (float*)smem;                              // [32][524]
  unsigned short* Pb = (unsigned short*)smem;            // [32][520], after S dies
  unsigned short* Pe = (unsigned short*)(smem + 33280);  // [32][584]

  const int tid  = threadIdx.x;
  const int lane = tid & 63;
  const int w    = tid >> 6;
  const int rq   = lane & 15;
  const int kq   = lane >> 4;
  const int id = blockIdx.x;
  const int t0 = ((id >> 3) & 15) * 32;
  const int b  = (id & 7) + 8 * (id >> 7);
  const int sw = w * 128;

  f16x8 q0[8], q1[8];
  {
    const size_t qo = ((size_t)(b * TS + t0 + rq) << 8) + kq * 8;
#pragma unroll
    for (int ks = 0; ks < 8; ++ks) {
      q0[ks] = *(const f16x8*)(qH + qo + ks * 32);
      q1[ks] = *(const f16x8*)(qH + qo + 4096 + ks * 32);
    }
  }

  f32x4 a0[8], a1[8];
#pragma unroll
  for (int ni = 0; ni < 8; ++ni) {
    a0[ni] = (f32x4){0.f, 0.f, 0.f, 0.f};
    a1[ni] = (f32x4){0.f, 0.f, 0.f, 0.f};
  }
  {
    const unsigned short* kp = kH + ((size_t)(b * TS + sw + rq) << 8) + kq * 8;
    f16x8 kA[8], kB[8];
#pragma unroll
    for (int ni = 0; ni < 8; ++ni) kA[ni] = *(const f16x8*)(kp + ni * 4096);
#pragma unroll
    for (int ni = 0; ni < 8; ++ni) kB[ni] = *(const f16x8*)(kp + ni * 4096 + 32);
#pragma unroll
    for (int ks = 0; ks < 8; ks += 2) {
      __builtin_amdgcn_s_setprio(1);
#pragma unroll
      for (int ni = 0; ni < 8; ++ni) {
        a0[ni] = __builtin_amdgcn_mfma_f32_16x16x32_f16(q0[ks], kA[ni], a0[ni], 0, 0, 0);
        a1[ni] = __builtin_amdgcn_mfma_f32_16x16x32_f16(q1[ks], kA[ni], a1[ni], 0, 0, 0);
        if (ks + 2 < 8) kA[ni] = *(const f16x8*)(kp + ni * 4096 + (ks + 2) * 32);
      }
#pragma unroll
      for (int ni = 0; ni < 8; ++ni) {
        a0[ni] = __builtin_amdgcn_mfma_f32_16x16x32_f16(q0[ks + 1], kB[ni], a0[ni], 0, 0, 0);
        a1[ni] = __builtin_amdgcn_mfma_f32_16x16x32_f16(q1[ks + 1], kB[ni], a1[ni], 0, 0, 0);
        if (ks + 3 < 8) kB[ni] = *(const f16x8*)(kp + ni * 4096 + (ks + 3) * 32);
      }
      __builtin_amdgcn_s_setprio(0);
    }
  }

  const int rbR = t0 - sw + 384;
  const unsigned short* ep = embB + ((size_t)(rbR + rq) << 8) + kq * 8;
  f16x8 eA[10], eB[10];
#pragma unroll
  for (int f = 0; f < 10; ++f) eA[f] = *(const f16x8*)(ep + f * 4096);
#pragma unroll
  for (int ni = 0; ni < 8; ++ni)
#pragma unroll
    for (int j = 0; j < 4; ++j) {
      S[(kq * 4 + j) * 524 + sw + ni * 16 + rq]        = a0[ni][j];
      S[(16 + kq * 4 + j) * 524 + sw + ni * 16 + rq]   = a1[ni][j];
    }
#pragma unroll
  for (int f = 0; f < 10; ++f) eB[f] = *(const f16x8*)(ep + f * 4096 + 32);

  f32x4 r0[9], r1[9];
#pragma unroll
  for (int ni = 0; ni < 9; ++ni) {
    r0[ni] = (f32x4){0.f, 0.f, 0.f, 0.f};
    r1[ni] = (f32x4){0.f, 0.f, 0.f, 0.f};
  }
#pragma unroll
  for (int ks = 0; ks < 8; ks += 2) {
    __builtin_amdgcn_s_setprio(1);
#pragma unroll
    for (int f = 0; f < 10; ++f) {
      if (f < 9) r0[f] = __builtin_amdgcn_mfma_f32_16x16x32_f16(q0[ks], eA[f], r0[f], 0, 0, 0);
      if (f > 0) r1[f - 1] = __builtin_amdgcn_mfma_f32_16x16x32_f16(q1[ks], eA[f], r1[f - 1], 0, 0, 0);
      if (ks + 2 < 8) eA[f] = *(const f16x8*)(ep + f * 4096 + (ks + 2) * 32);
    }
#pragma unroll
    for (int f = 0; f < 10; ++f) {
      if (f < 9) r0[f] = __builtin_amdgcn_mfma_f32_16x16x32_f16(q0[ks + 1], eB[f], r0[f], 0, 0, 0);
      if (f > 0) r1[f - 1] = __builtin_amdgcn_mfma_f32_16x16x32_f16(q1[ks + 1], eB[f], r1[f - 1], 0, 0, 0);
      if (ks + 3 < 8) eB[f] = *(const f16x8*)(ep + f * 4096 + (ks + 3) * 32);
    }
    __builtin_amdgcn_s_setprio(0);
  }

  asm volatile("s_waitcnt lgkmcnt(0)" ::: "memory");
  __builtin_amdgcn_sched_barrier(0);
#pragma unroll
  for (int ni = 0; ni < 9; ++ni)
#pragma unroll
    for (int j = 0; j < 4; ++j) {
      int tp  = kq * 4 + j;
      int slw = tp + 127 - (ni * 16 + rq);
      if (slw >= 0 && slw < 128) {
        S[tp * 524 + sw + slw]        += r0[ni][j];
        S[(16 + tp) * 524 + sw + slw] += r1[ni][j];
      }
    }
  __syncthreads();

  const int row16 = tid >> 4, tx = tid & 15;
  float p0[32], p1[32];
  float invl0, invl1;
#pragma unroll
  for (int pass = 0; pass < 2; ++pass) {
    float* pp = pass ? p1 : p0;
    const float* Srow = S + (pass * 16 + row16) * 524 + tx * 4;
    float mx = -3.0e38f, l = 0.f;
#pragma unroll
    for (int i = 0; i < 8; ++i) {
      float4 v = *(const float4*)(Srow + i * 64);
      pp[4*i+0] = v.x; pp[4*i+1] = v.y; pp[4*i+2] = v.z; pp[4*i+3] = v.w;
    }
#pragma unroll
    for (int i = 0; i < 32; ++i) mx = fmaxf(mx, pp[i]);
    mx = fmaxf(mx, __shfl_xor(mx, 1)); mx = fmaxf(mx, __shfl_xor(mx, 2));
    mx = fmaxf(mx, __shfl_xor(mx, 4)); mx = fmaxf(mx, __shfl_xor(mx, 8));
#pragma unroll
    for (int i = 0; i < 32; ++i) { pp[i] = __expf(pp[i] - mx); l += pp[i]; }
    l += __shfl_xor(l, 1); l += __shfl_xor(l, 2);
    l += __shfl_xor(l, 4); l += __shfl_xor(l, 8);
    if (pass) invl1 = 1.0f / l; else invl0 = 1.0f / l;
  }

  {
    const float xb2c = xb2p[0];
    const float* vxp = vxm + b * TS;
    const float* xp  = xin + (size_t)b * 3 * TS;
    float w0s = 0.f, xa00 = 0.f, xa01 = 0.f, xa02 = 0.f;
    float w1s = 0.f, xa10 = 0.f, xa11 = 0.f, xa12 = 0.f;
#pragma unroll
    for (int i = 0; i < 8; ++i) {
      int s = i * 64 + tx * 4;
      float4 vv = *(const float4*)(vxp + s);
      float4 x0 = *(const float4*)(xp + s);
      float4 x1 = *(const float4*)(xp + TS + s);
      float4 x2 = *(const float4*)(xp + 2 * TS + s);
      float vb0 = vv.x + xb2c, vb1 = vv.y + xb2c, vb2 = vv.z + xb2c, vb3 = vv.w + xb2c;
      float wv;
      wv = p0[4*i+0] * vb0; w0s += wv; xa00 = fmaf(wv, x0.x, xa00); xa01 = fmaf(wv, x1.x, xa01); xa02 = fmaf(wv, x2.x, xa02);
      wv = p0[4*i+1] * vb1; w0s += wv; xa00 = fmaf(wv, x0.y, xa00); xa01 = fmaf(wv, x1.y, xa01); xa02 = fmaf(wv, x2.y, xa02);
      wv = p0[4*i+2] * vb2; w0s += wv; xa00 = fmaf(wv, x0.z, xa00); xa01 = fmaf(wv, x1.z, xa01); xa02 = fmaf(wv, x2.z, xa02);
      wv = p0[4*i+3] * vb3; w0s += wv; xa00 = fmaf(wv, x0.w, xa00); xa01 = fmaf(wv, x1.w, xa01); xa02 = fmaf(wv, x2.w, xa02);
      wv = p1[4*i+0] * vb0; w1s += wv; xa10 = fmaf(wv, x0.x, xa10); xa11 = fmaf(wv, x1.x, xa11); xa12 = fmaf(wv, x2.x, xa12);
      wv = p1[4*i+1] * vb1; w1s += wv; xa10 = fmaf(wv, x0.y, xa10); xa11 = fmaf(wv, x1.y, xa11); xa12 = fmaf(wv, x2.y, xa12);
      wv = p1[4*i+2] * vb2; w1s += wv; xa10 = fmaf(wv, x0.z, xa10); xa11 = fmaf(wv, x1.z, xa11); xa12 = fmaf(wv, x2.z, xa12);
      wv = p1[4*i+3] * vb3; w1s += wv; xa10 = fmaf(wv, x0.w, xa10); xa11 = fmaf(wv, x1.w, xa11); xa12 = fmaf(wv, x2.w, xa12);
    }
#pragma unroll
    for (int m = 1; m < 16; m <<= 1) {
      w0s += __shfl_xor(w0s, m); xa00 += __shfl_xor(xa00, m);
      xa01 += __shfl_xor(xa01, m); xa02 += __shfl_xor(xa02, m);
      w1s += __shfl_xor(w1s, m); xa10 += __shfl_xor(xa10, m);
      xa11 += __shfl_xor(xa11, m); xa12 += __shfl_xor(xa12, m);
    }
    if (tx == 0) {
      int ta = t0 + row16, tb2 = t0 + 16 + row16;
      float wsa = w0s * invl0, wsb = w1s * invl1;
      xout[(b * 3 + 0) * TS + ta] = xp[ta]          * (1.0f + wsa) - xa00 * invl0;
      xout[(b * 3 + 1) * TS + ta] = xp[TS + ta]     * (1.0f + wsa) - xa01 * invl0;
      xout[(b * 3 + 2) * TS + ta] = xp[2 * TS + ta] * (1.0f + wsa) - xa02 * invl0;
      xout[(b * 3 + 0) * TS + tb2] = xp[tb2]          * (1.0f + wsb) - xa10 * invl1;
      xout[(b * 3 + 1) * TS + tb2] = xp[TS + tb2]     * (1.0f + wsb) - xa11 * invl1;
      xout[(b * 3 + 2) * TS + tb2] = xp[2 * TS + tb2] * (1.0f + wsb) - xa12 * invl1;
    }
  }

  // ---- T14 issue-early: phase-2 initial Vt/embT fragments (no Pb/Pe dep) ----
  const int n0 = w * 64;
  const unsigned short* vtp = vtH + ((size_t)(b * 256 + n0 + rq) << 9) + kq * 8;
  const unsigned short* etp = embT + (size_t)(n0 + rq) * ETS + t0 + kq * 8;
  f16x8 vA[4], vB[4], gA[4], gB[4];
#pragma unroll
  for (int ni = 0; ni < 4; ++ni) {
    vA[ni] = *(const f16x8*)(vtp + ni * 8192);
    gA[ni] = *(const f16x8*)(etp + ni * 16 * ETS);
    vB[ni] = *(const f16x8*)(vtp + ni * 8192 + 32);
    gB[ni] = *(const f16x8*)(etp + ni * 16 * ETS + 32);
  }
  __builtin_amdgcn_sched_barrier(0);   // pin loads above the barrier chain

  __syncthreads();   // B2: everyone done reading S -> Pb/Pe may overwrite

  {
    unsigned int* pz = (unsigned int*)Pe;
    for (int i = tid; i < 9344; i += 256) pz[i] = 0u;
  }
  __syncthreads();   // B2b: Pe zeroed before scatter

#pragma unroll
  for (int pass = 0; pass < 2; ++pass) {
    const float* pp = pass ? p1 : p0;
    const float il = pass ? invl1 : invl0;
    const int row = pass * 16 + row16;
    unsigned short* pbrow = Pb + row * 520 + tx * 4;
    unsigned short* perow = Pe + row * 584 + row + 511;
#pragma unroll
    for (int i = 0; i < 8; ++i) {
      int s = i * 64 + tx * 4;
      ushort4 pu;
      pu.x = f2h(pp[4*i+0] * il); pu.y = f2h(pp[4*i+1] * il);
      pu.z = f2h(pp[4*i+2] * il); pu.w = f2h(pp[4*i+3] * il);
      *(ushort4*)(pbrow + i * 64) = pu;
      perow[-(s + 0)] = pu.x; perow[-(s + 1)] = pu.y;
      perow[-(s + 2)] = pu.z; perow[-(s + 3)] = pu.w;
    }
  }
  __syncthreads();   // B3: Pb/Pe ready

  f32x4 o0[4], o1[4];
#pragma unroll
  for (int ni = 0; ni < 4; ++ni) {
    o0[ni] = (f32x4){0.f, 0.f, 0.f, 0.f};
    o1[ni] = (f32x4){0.f, 0.f, 0.f, 0.f};
  }
  {
    const unsigned short* pb0 = Pb + rq * 520 + kq * 8;
    const unsigned short* pb1 = Pb + (16 + rq) * 520 + kq * 8;
    const unsigned short* pe0 = Pe + rq * 584 + kq * 8;
    const unsigned short* pe1 = Pe + (16 + rq) * 584 + kq * 8;
#pragma unroll
    for (int kk = 0; kk < 16; kk += 2) {
      f16x8 pa0 = *(const f16x8*)(pb0 + kk * 32);
      f16x8 pa1 = *(const f16x8*)(pb1 + kk * 32);
      __builtin_amdgcn_s_setprio(1);
#pragma unroll
      for (int ni = 0; ni < 4; ++ni) {
        o0[ni] = __builtin_amdgcn_mfma_f32_16x16x32_f16(pa0, vA[ni], o0[ni], 0, 0, 0);
        o1[ni] = __builtin_amdgcn_mfma_f32_16x16x32_f16(pa1, vA[ni], o1[ni], 0, 0, 0);
        if (kk + 2 < 16) vA[ni] = *(const f16x8*)(vtp + ni * 8192 + (kk + 2) * 32);
      }
      f16x8 pe0f = *(const f16x8*)(pe0 + kk * 32);
      f16x8 pe1f = *(const f16x8*)(pe1 + kk * 32);
#pragma unroll
      for (int ni = 0; ni < 4; ++ni) {
        o0[ni] = __builtin_amdgcn_mfma_f32_16x16x32_f16(pe0f, gA[ni], o0[ni], 0, 0, 0);
        o1[ni] = __builtin_amdgcn_mfma_f32_16x16x32_f16(pe1f, gA[ni], o1[ni], 0, 0, 0);
        if (kk + 2 < 17) gA[ni] = *(const f16x8*)(etp + ni * 16 * ETS + (kk + 2) * 32);
      }
      f16x8 pc0 = *(const f16x8*)(pb0 + (kk + 1) * 32);
      f16x8 pc1 = *(const f16x8*)(pb1 + (kk + 1) * 32);
#pragma unroll
      for (int ni = 0; ni < 4; ++ni) {
        o0[ni] = __builtin_amdgcn_mfma_f32_16x16x32_f16(pc0, vB[ni], o0[ni], 0, 0, 0);
        o1[ni] = __builtin_amdgcn_mfma_f32_16x16x32_f16(pc1, vB[ni], o1[ni], 0, 0, 0);
        if (kk + 3 < 16) vB[ni] = *(const f16x8*)(vtp + ni * 8192 + (kk + 3) * 32);
      }
      f16x8 pd0 = *(const f16x8*)(pe0 + (kk + 1) * 32);
      f16x8 pd1 = *(const f16x8*)(pe1 + (kk + 1) * 32);
#pragma unroll
      for (int ni = 0; ni < 4; ++ni) {
        o0[ni] = __builtin_amdgcn_mfma_f32_16x16x32_f16(pd0, gB[ni], o0[ni], 0, 0, 0);
        o1[ni] = __builtin_amdgcn_mfma_f32_16x16x32_f16(pd1, gB[ni], o1[ni], 0, 0, 0);
        if (kk + 3 < 17) gB[ni] = *(const f16x8*)(etp + ni * 16 * ETS + (kk + 3) * 32);
      }
      __builtin_amdgcn_s_setprio(0);
    }
    f16x8 pt0 = *(const f16x8*)(pe0 + 16 * 32);
    f16x8 pt1 = *(const f16x8*)(pe1 + 16 * 32);
#pragma unroll
    for (int ni = 0; ni < 4; ++ni) {
      o0[ni] = __builtin_amdgcn_mfma_f32_16x16x32_f16(pt0, gA[ni], o0[ni], 0, 0, 0);
      o1[ni] = __builtin_amdgcn_mfma_f32_16x16x32_f16(pt1, gA[ni], o1[ni], 0, 0, 0);
    }
  }

  {
#pragma unroll
    for (int ni = 0; ni < 4; ++ni) {
      int hh = n0 + ni * 16 + rq;
      size_t base = (((size_t)(b * 256 + hh)) << 9) + t0 + kq * 4;
      float4 hv0 = *(const float4*)(hin + base);
      float4 ov0;
      ov0.x = hv0.x + o0[ni][0];
      ov0.y = hv0.y + o0[ni][1];
      ov0.z = hv0.z + o0[ni][2];
      ov0.w = hv0.w + o0[ni][3];
      *(float4*)(hout + base) = ov0;
      float4 hv1 = *(const float4*)(hin + base + 16);
      float4 ov1;
      ov1.x = hv1.x + o1[ni][0];
      ov1.y = hv1.y + o1[ni][1];
      ov1.z = hv1.z + o1[ni][2];
      ov1.w = hv1.w + o1[ni][3];
      *(float4*)(hout + base + 16) = ov1;
    }
  }
}

// ---------------------------------------------------------------------------
extern "C" void kernel_launch(void* const* d_in, const int* in_sizes, int n_in,
                              void* d_out, int out_size, void* d_ws, size_t ws_size,
                              hipStream_t stream)
{
  const float* x   = (const float*)d_in[0];
  const float* h   = (const float*)d_in[1];
  const float* qW1 = (const float*)d_in[2];
  const float* qb1 = (const float*)d_in[3];
  const float* qW2 = (const float*)d_in[4];
  const float* qb2 = (const float*)d_in[5];
  const float* kW1 = (const float*)d_in[6];
  const float* kb1 = (const float*)d_in[7];
  const float* kW2 = (const float*)d_in[8];
  const float* kb2 = (const float*)d_in[9];
  const float* vW1 = (const float*)d_in[10];
  const float* vb1 = (const float*)d_in[11];
  const float* vW2 = (const float*)d_in[12];
  const float* vb2 = (const float*)d_in[13];
  const float* xW1 = (const float*)d_in[14];
  const float* xb1 = (const float*)d_in[15];
  const float* xW2 = (const float*)d_in[16];
  const float* xb2 = (const float*)d_in[17];
  const float* teW = (const float*)d_in[18];
  const float* teb = (const float*)d_in[19];

  // ws layout (fp16 except vx) ~66 MB
  unsigned short* cur = (unsigned short*)d_ws;
  unsigned short* embB = cur; cur += 1024 * 256;
  unsigned short* embT = cur; cur += 256 * ETS;
  unsigned short* SC   = cur; cur += 1024 * 256;
  unsigned short* hmH  = cur; cur += (size_t)24576 * 256;
  unsigned short* WtH  = cur; cur += 8 * 65536;
  unsigned short* qHp  = cur; cur += (size_t)24576 * 256;
  unsigned short* kHp  = cur; cur += (size_t)24576 * 256;
  unsigned short* vHp  = cur; cur += (size_t)24576 * 256;
  unsigned short* vtH  = cur; cur += (size_t)24576 * 256;
  float* vx = (float*)cur;                                // 24576 f32

  float* xout = (float*)d_out;                // [48,3,512]
  float* hout = xout + NB * 3 * TS;           // [48,256,512]

  // 1) all preps in one launch (sincos | h->hmH+vx | 8x weight transpose)
  k_prep<<<1792, 256, 0, stream>>>(h, hmH, vx,
                                   qW1, qW2, kW1, kW2, vW1, vW2, xW1, teW,
                                   WtH, SC);

  // 2) fused 2-layer MLPs: q, k, v (v also writes Vt transposed)
  {
    MJobs jm{{{hmH, WtH + 0 * 65536, qb1, WtH + 1 * 65536, qb2, qHp, nullptr},
              {hmH, WtH + 2 * 65536, kb1, WtH + 3 * 65536, kb2, kHp, nullptr},
              {hmH, WtH + 4 * 65536, vb1, WtH + 5 * 65536, vb2, vHp, vtH}}};
    k_mlp2<<<dim3(384, 3), 256, 0, stream>>>(jm);
  }

  // 3) emb GEMM (SC @ teW^T -> embB + embT) and x-MLP layer1+vx, one launch
  {
    GJobs jg{{{SC,  WtH + 7 * 65536, teb, embB, embT, nullptr, nullptr, 0, 1024},
              {vHp, WtH + 6 * 65536, xb1, nullptr, nullptr, xW2, vx, 1, 24576}}};
    k_gemm<<<dim3(192, 1, 2), 512, 0, stream>>>(jg);
  }

  // 4) fused attention (+ setprio / issue-early)
  k_attn6<<<768, 256, 0, stream>>>(x, h, qHp, kHp, vtH, vx, xb2,
                                   embB, embT, xout, hout);
}